// Round 4
// baseline (2185.447 us; speedup 1.0000x reference)
//
#include <hip/hip_runtime.h>
#include <cmath>

// Shapes: B=128, D=192, DEPTH=12, H=3(hd=64), E=4, N=65(tokens), NC=100, WIN_HALF=3
#define ROWS 8320
#define DD   192

typedef __attribute__((ext_vector_type(8))) short bhalf8;
typedef __attribute__((ext_vector_type(4))) float floatx4;

#define GLD16(gp, lp) __builtin_amdgcn_global_load_lds( \
    (const __attribute__((address_space(1))) void*)(gp), \
    (__attribute__((address_space(3))) void*)(lp), 16, 0, 0)

#define MFMA_BF16 __builtin_amdgcn_mfma_f32_16x16x32_bf16

__device__ __forceinline__ float gelu_f(float x) {
    return 0.5f * x * (1.0f + erff(x * 0.70710678118654752440f));
}
__device__ __forceinline__ ushort f2b(float f) {
    unsigned u = __float_as_uint(f);
    unsigned r = (u + 0x7FFFu + ((u >> 16) & 1u)) >> 16;
    return (ushort)r;
}
__device__ __forceinline__ float b2f(ushort u) {
    return __uint_as_float(((unsigned)u) << 16);
}

// block-wide sum for blockDim.x == 192
__device__ __forceinline__ float blk_sum_192(float v, float* sbuf) {
    int tid = threadIdx.x;
    sbuf[tid] = v;
    __syncthreads();
    for (int off = 96; off >= 3; off >>= 1) {
        if (tid < off) sbuf[tid] += sbuf[tid + off];
        __syncthreads();
    }
    float r = sbuf[0] + sbuf[1] + sbuf[2];
    __syncthreads();
    return r;
}

// ---------------- weight split-convert: flat [rows*K] fp32 -> [pair][hi8|lo8] ----------------
__global__ __launch_bounds__(256) void cvt_split_kernel(
    const float* __restrict__ s, ushort* __restrict__ d, long npairs)
{
    long i = (long)blockIdx.x * 256 + threadIdx.x;
    if (i >= npairs) return;
    const float* sp = s + i * 8;
    ushort* dp = d + i * 16;
    #pragma unroll
    for (int j = 0; j < 8; j++) {
        float v = sp[j];
        ushort hi = f2b(v);
        float lo = v - b2f(hi);
        dp[j] = hi;
        dp[8 + j] = f2b(lo);
    }
}

// e_w2 (12,4,192,384) -> split-pair layout [l][n][K'=1536] with col = e*384+k
__global__ __launch_bounds__(256) void permw2_kernel(
    const float* __restrict__ s, ushort* __restrict__ d)
{
    long i = (long)blockIdx.x * 256 + threadIdx.x;   // (l, n, p), p in 0..191
    if (i >= (long)12 * 192 * 192) return;
    int l = (int)(i / (192 * 192));
    int rem = (int)(i % (192 * 192));
    int n = rem / 192, p = rem % 192;
    int c0 = p * 8;
    int e = c0 / 384, k0 = c0 % 384;
    const float* sp = s + (((size_t)l * 4 + e) * 192 + n) * 384 + k0;
    ushort* dp = d + i * 16;
    #pragma unroll
    for (int j = 0; j < 8; j++) {
        float v = sp[j];
        ushort hi = f2b(v);
        float lo = v - b2f(hi);
        dp[j] = hi;
        dp[8 + j] = f2b(lo);
    }
}

// ---------------- patch embed + LN + cls + pos (fp32) ----------------
__global__ __launch_bounds__(192) void embed_kernel(
    const float* __restrict__ x, const float* __restrict__ conv_w,
    const float* __restrict__ conv_b, const float* __restrict__ pe_g,
    const float* __restrict__ pe_b, const float* __restrict__ cls_tok,
    const float* __restrict__ pos, float* __restrict__ t)
{
    __shared__ float patch[48];
    __shared__ float red[192];
    int blk = blockIdx.x;
    int b = blk / 65, n = blk % 65;
    int tid = threadIdx.x;
    if (n == 0) {
        t[(size_t)b * 65 * DD + tid] = cls_tok[tid] + pos[tid];
        return;
    }
    int p = n - 1, gy = p / 8, gx = p % 8;
    if (tid < 48) {
        int c = tid / 16, iy = (tid % 16) / 4, ix = tid % 4;
        patch[tid] = x[((size_t)b * 3 + c) * 1024 + (size_t)(gy * 4 + iy) * 32 + (gx * 4 + ix)];
    }
    __syncthreads();
    float s = conv_b[tid];
    const float* w = conv_w + (size_t)tid * 48;
    #pragma unroll
    for (int f = 0; f < 48; f++) s += patch[f] * w[f];
    float mean = blk_sum_192(s, red) * (1.0f / 192.0f);
    float d = s - mean;
    float var = blk_sum_192(d * d, red) * (1.0f / 192.0f);
    float o = d * rsqrtf(var + 1e-5f) * pe_g[tid] + pe_b[tid];
    t[((size_t)b * 65 + n) * DD + tid] = o + pos[(size_t)n * DD + tid];
}

// ---------------- LayerNorm (+optional fused gate): fp32 in (strided) ----------------
// outputs: yf fp32 (opt), ysp split-pair (opt); gate: softmax(y@gwm^T+gb) top2 -> gwout (opt)
__global__ __launch_bounds__(192) void ln_kernel(
    const float* __restrict__ in, float* __restrict__ yf, ushort* __restrict__ ysp,
    const float* __restrict__ g, const float* __restrict__ bb, long in_stride,
    const float* __restrict__ gwm, const float* __restrict__ gb,
    float* __restrict__ gwout)
{
    __shared__ float red[192];
    __shared__ float gp[3][4];
    int r = blockIdx.x, tid = threadIdx.x;
    float v = in[(size_t)r * in_stride + tid];
    float mean = blk_sum_192(v, red) * (1.0f / 192.0f);
    float d = v - mean;
    float var = blk_sum_192(d * d, red) * (1.0f / 192.0f);
    float o = d * rsqrtf(var + 1e-5f) * g[tid] + bb[tid];
    if (yf) yf[(size_t)r * DD + tid] = o;
    if (ysp) {
        int p = tid >> 3, pos = tid & 7;
        ushort hi = f2b(o);
        ysp[(size_t)r * 384 + p * 16 + pos] = hi;
        ysp[(size_t)r * 384 + p * 16 + 8 + pos] = f2b(o - b2f(hi));
    }
    if (gwm) {
        float p0 = o * gwm[tid], p1 = o * gwm[192 + tid];
        float p2 = o * gwm[384 + tid], p3 = o * gwm[576 + tid];
        #pragma unroll
        for (int off = 32; off > 0; off >>= 1) {
            p0 += __shfl_down(p0, off);
            p1 += __shfl_down(p1, off);
            p2 += __shfl_down(p2, off);
            p3 += __shfl_down(p3, off);
        }
        if ((tid & 63) == 0) {
            int w = tid >> 6;
            gp[w][0] = p0; gp[w][1] = p1; gp[w][2] = p2; gp[w][3] = p3;
        }
        __syncthreads();
        if (tid == 0) {
            float g4[4];
            #pragma unroll
            for (int e = 0; e < 4; e++) g4[e] = gp[0][e] + gp[1][e] + gp[2][e] + gb[e];
            float mx = fmaxf(fmaxf(g4[0], g4[1]), fmaxf(g4[2], g4[3]));
            float ex[4];
            #pragma unroll
            for (int e = 0; e < 4; e++) ex[e] = expf(g4[e] - mx);
            int i0 = 0;
            #pragma unroll
            for (int e = 1; e < 4; e++) if (ex[e] > ex[i0]) i0 = e;
            int i1 = (i0 == 0) ? 1 : 0;
            #pragma unroll
            for (int e = 0; e < 4; e++) if (e != i0 && ex[e] > ex[i1]) i1 = e;
            float denom = ex[i0] + ex[i1];
            float out[4] = {0.f, 0.f, 0.f, 0.f};
            out[i0] = ex[i0] / denom; out[i1] = ex[i1] / denom;
            #pragma unroll
            for (int e = 0; e < 4; e++) gwout[(size_t)r * 4 + e] = out[e];
        }
    }
}

// ---------------- split-bf16 MFMA GEMM (qkv / proj) ----------------
// MODE 0: qkv  -> outF fp32 [M][Nn]
// MODE 2: proj -> t[r*192+n] += scale[0]*(acc + bias[n])
template <int MODE>
__global__ __launch_bounds__(256) void mfma_gemm(
    const ushort* __restrict__ A, const ushort* __restrict__ W,
    int Nn, int Ktot,
    float* __restrict__ outF, float* __restrict__ t,
    const float* __restrict__ bias, const float* __restrict__ scale)
{
    __shared__ __align__(16) ushort As[64 * 192];   // 64 rows x 24 chunks(16B)
    __shared__ __align__(16) ushort Ws[64 * 192];
    const int tid = threadIdx.x;
    const int lane = tid & 63, wave = tid >> 6;
    const int m0 = blockIdx.x * 64, n0 = blockIdx.y * 64;
    const int wm = (wave & 1) * 32, wn = (wave >> 1) * 32;
    const int lr = lane & 15, quad = lane >> 4;

    floatx4 zero = {0.f, 0.f, 0.f, 0.f};
    floatx4 acc[2][2];
    acc[0][0] = zero; acc[0][1] = zero; acc[1][0] = zero; acc[1][1] = zero;

    const int nstage = Ktot / 96;
    const size_t rstride = (size_t)Ktot * 2;

    for (int st = 0; st < nstage; st++) {
        #pragma unroll
        for (int j = 0; j < 6; j++) {
            int sidx = (wave * 6 + j) * 64 + lane;
            int row = sidx / 24, c = sidx % 24;
            int gc = st * 24 + (c ^ (row & 7));
            GLD16(A + (size_t)(m0 + row) * rstride + gc * 8,
                  (char*)As + (size_t)(wave * 6 + j) * 1024);
            GLD16(W + (size_t)(n0 + row) * rstride + gc * 8,
                  (char*)Ws + (size_t)(wave * 6 + j) * 1024);
        }
        __syncthreads();
        #pragma unroll
        for (int m = 0; m < 3; m++) {
            int p = m * 4 + quad;
            bhalf8 ah[2], al[2], wh[2], wl[2];
            #pragma unroll
            for (int ti = 0; ti < 2; ti++) {
                int row = wm + ti * 16 + lr;
                ah[ti] = *(const bhalf8*)(As + (row * 24 + ((2 * p) ^ (row & 7))) * 8);
                al[ti] = *(const bhalf8*)(As + (row * 24 + ((2 * p + 1) ^ (row & 7))) * 8);
                int col = wn + ti * 16 + lr;
                wh[ti] = *(const bhalf8*)(Ws + (col * 24 + ((2 * p) ^ (col & 7))) * 8);
                wl[ti] = *(const bhalf8*)(Ws + (col * 24 + ((2 * p + 1) ^ (col & 7))) * 8);
            }
            #pragma unroll
            for (int ti = 0; ti < 2; ti++)
                #pragma unroll
                for (int tj = 0; tj < 2; tj++) {
                    acc[ti][tj] = MFMA_BF16(ah[ti], wh[tj], acc[ti][tj], 0, 0, 0);
                    acc[ti][tj] = MFMA_BF16(ah[ti], wl[tj], acc[ti][tj], 0, 0, 0);
                    acc[ti][tj] = MFMA_BF16(al[ti], wh[tj], acc[ti][tj], 0, 0, 0);
                }
        }
        __syncthreads();
    }

    float sc = (MODE == 2) ? scale[0] : 0.f;
    #pragma unroll
    for (int ti = 0; ti < 2; ti++)
        #pragma unroll
        for (int tj = 0; tj < 2; tj++)
            #pragma unroll
            for (int r = 0; r < 4; r++) {
                int grow = m0 + wm + ti * 16 + quad * 4 + r;
                int gcol = n0 + wn + tj * 16 + lr;
                float v = acc[ti][tj][r];
                if (MODE == 0) {
                    outF[(size_t)grow * Nn + gcol] = v;
                } else {
                    t[(size_t)grow * DD + gcol] += sc * (v + bias[gcol]);
                }
            }
}

// ---------------- fused MoE: t += mlp_sc * sum_e gw[e]*(gelu(y@w1_e^T+b1_e)@w2_e^T + b2_e)
// grid 260 blocks, 256 thr. Block owns 32 rows x all 192 out cols.
// Loops 48 chunks of 32 h-cols; h stays in LDS (split-pair); weights streamed via GLD16.
__global__ __launch_bounds__(256) void moe_kernel(
    const ushort* __restrict__ ysp, const ushort* __restrict__ w1,
    const ushort* __restrict__ w2, const float* __restrict__ b1,
    const float* __restrict__ b2, const float* __restrict__ scale,
    const float* __restrict__ gw, float* __restrict__ t)
{
    __shared__ __align__(16) ushort As[32 * 384];   // 32 rows x 48 chunks  (24KB)
    __shared__ __align__(16) ushort W1s[32 * 384];  // 32 h-cols x 48 chunks (24KB)
    __shared__ __align__(16) ushort W2s[192 * 64];  // 192 cols x 8 chunks   (24KB)
    __shared__ __align__(16) ushort Hs[32 * 64];    // 32 rows x 8 chunks    (4KB)
    const int tid = threadIdx.x;
    const int lane = tid & 63, wave = tid >> 6;
    const int lr = lane & 15, quad = lane >> 4;
    const int r0 = blockIdx.x * 32;
    const int wr = (wave & 1) * 16;        // row tile base (both gemms)
    const int wc1 = (wave >> 1) * 16;      // gemm1 col base (h cols 0..31)
    const int wc2 = (wave >> 1) * 96;      // gemm2 col base (out cols 0..191)

    // stage A (ysp rows r0..r0+31, full K=192 split = 48 chunks)
    #pragma unroll
    for (int i = 0; i < 6; i++) {
        int s = (wave * 6 + i) * 64 + lane;
        int rr = s / 48, c = s % 48;
        GLD16(ysp + (size_t)(r0 + rr) * 384 + (c ^ (rr & 7)) * 8, (char*)As + s * 16);
    }
    // stage W1[0]
    #pragma unroll
    for (int i = 0; i < 6; i++) {
        int s = (wave * 6 + i) * 64 + lane;
        int rr = s / 48, c = s % 48;
        GLD16(w1 + (size_t)rr * 384 + (c ^ (rr & 7)) * 8, (char*)W1s + s * 16);
    }
    __syncthreads();

    floatx4 zero = {0.f, 0.f, 0.f, 0.f};
    floatx4 acc2[6];
    #pragma unroll
    for (int j = 0; j < 6; j++) acc2[j] = zero;

    for (int nc = 0; nc < 48; nc++) {
        // issue W2[nc] loads (fly during gemm1)
        #pragma unroll
        for (int i = 0; i < 6; i++) {
            int s = (wave * 6 + i) * 64 + lane;
            int n = s >> 3, c = s & 7;
            GLD16(w2 + (size_t)n * 3072 + (8 * nc + (c ^ (n & 7))) * 8, (char*)W2s + s * 16);
        }
        // gemm1: h_chunk[32][32], this wave computes 16x16 tile (wr, wc1)
        floatx4 acc1 = zero;
        #pragma unroll
        for (int m = 0; m < 6; m++) {
            int ch = 8 * m + 2 * quad;
            int ar = wr + lr;
            bhalf8 ah = *(const bhalf8*)(As + ((size_t)ar * 48 + (ch ^ (ar & 7))) * 8);
            bhalf8 al = *(const bhalf8*)(As + ((size_t)ar * 48 + ((ch + 1) ^ (ar & 7))) * 8);
            int cr = wc1 + lr;
            bhalf8 wh = *(const bhalf8*)(W1s + ((size_t)cr * 48 + (ch ^ (cr & 7))) * 8);
            bhalf8 wl = *(const bhalf8*)(W1s + ((size_t)cr * 48 + ((ch + 1) ^ (cr & 7))) * 8);
            acc1 = MFMA_BF16(ah, wh, acc1, 0, 0, 0);
            acc1 = MFMA_BF16(ah, wl, acc1, 0, 0, 0);
            acc1 = MFMA_BF16(al, wh, acc1, 0, 0, 0);
        }
        // epilogue: gelu + gate weight -> Hs (split-pair, XOR-swizzled)
        {
            int e = nc / 12;
            #pragma unroll
            for (int r = 0; r < 4; r++) {
                int hrow = wr + quad * 4 + r;
                int hcol = wc1 + lr;
                float v = acc1[r] + b1[32 * nc + hcol];
                v = gelu_f(v) * gw[(size_t)(r0 + hrow) * 4 + e];
                int p = hcol >> 3, pos = hcol & 7;
                ushort hi = f2b(v);
                Hs[((size_t)hrow * 8 + ((2 * p) ^ (hrow & 7))) * 8 + pos] = hi;
                Hs[((size_t)hrow * 8 + ((2 * p + 1) ^ (hrow & 7))) * 8 + pos] = f2b(v - b2f(hi));
            }
        }
        __syncthreads();   // W2 loaded, Hs visible, W1 reads done
        if (nc < 47) {     // prefetch W1[nc+1] during gemm2
            int nn = nc + 1;
            #pragma unroll
            for (int i = 0; i < 6; i++) {
                int s = (wave * 6 + i) * 64 + lane;
                int rr = s / 48, c = s % 48;
                GLD16(w1 + (size_t)(32 * nn + rr) * 384 + (c ^ (rr & 7)) * 8,
                      (char*)W1s + s * 16);
            }
        }
        // gemm2: out[32][192] partial, K=32; wave tiles rows wr, cols wc2+tj*16
        {
            int ch = 2 * quad;
            int ar = wr + lr;
            bhalf8 ah = *(const bhalf8*)(Hs + ((size_t)ar * 8 + (ch ^ (ar & 7))) * 8);
            bhalf8 al = *(const bhalf8*)(Hs + ((size_t)ar * 8 + ((ch + 1) ^ (ar & 7))) * 8);
            #pragma unroll
            for (int tj = 0; tj < 6; tj++) {
                int cr = wc2 + tj * 16 + lr;
                bhalf8 wh = *(const bhalf8*)(W2s + ((size_t)cr * 8 + (ch ^ (cr & 7))) * 8);
                bhalf8 wl = *(const bhalf8*)(W2s + ((size_t)cr * 8 + ((ch + 1) ^ (cr & 7))) * 8);
                acc2[tj] = MFMA_BF16(ah, wh, acc2[tj], 0, 0, 0);
                acc2[tj] = MFMA_BF16(ah, wl, acc2[tj], 0, 0, 0);
                acc2[tj] = MFMA_BF16(al, wh, acc2[tj], 0, 0, 0);
            }
        }
        __syncthreads();   // W1[nc+1] ready; W2s/Hs reads done before overwrite
    }

    float sc = scale[0];
    #pragma unroll
    for (int tj = 0; tj < 6; tj++) {
        int gcol = wc2 + tj * 16 + lr;
        #pragma unroll
        for (int r = 0; r < 4; r++) {
            int grow = r0 + wr + quad * 4 + r;
            float bb = gw[(size_t)grow * 4 + 0] * b2[gcol]
                     + gw[(size_t)grow * 4 + 1] * b2[192 + gcol]
                     + gw[(size_t)grow * 4 + 2] * b2[384 + gcol]
                     + gw[(size_t)grow * 4 + 3] * b2[576 + gcol];
            t[(size_t)grow * DD + gcol] += sc * (acc2[tj][r] + bb);
        }
    }
}

// ---------------- banded attention: fp32 qkv in, split-pair o out ----------------
__global__ __launch_bounds__(256) void attn_kernel(
    const float* __restrict__ qkv, const float* __restrict__ temp,
    ushort* __restrict__ o)
{
    __shared__ float q[65][64], k[65][64], v[65][64];
    __shared__ float p[65][8];
    int bh = blockIdx.x;
    int b = bh / 3, h = bh % 3;
    int tid = threadIdx.x;
    float coef = 0.125f / temp[h];
    const float* base = qkv + (size_t)b * 65 * 576 + h * 64;
    for (int idx = tid; idx < 65 * 64; idx += 256) {
        int i = idx >> 6, d = idx & 63;
        q[i][d] = base[(size_t)i * 576 + d];
        k[i][d] = base[(size_t)i * 576 + 192 + d];
        v[i][d] = base[(size_t)i * 576 + 384 + d];
    }
    __syncthreads();
    if (tid < 65) {
        int i = tid;
        float sc[7];
        float mx = -1e30f;
        #pragma unroll
        for (int jo = 0; jo < 7; jo++) {
            int j = i - 3 + jo;
            if (j >= 0 && j < 65) {
                float s = 0.f;
                #pragma unroll
                for (int d = 0; d < 64; d++) s += q[i][d] * k[j][d];
                sc[jo] = s * coef;
                mx = fmaxf(mx, sc[jo]);
            } else sc[jo] = -1e30f;
        }
        float sum = 0.f;
        #pragma unroll
        for (int jo = 0; jo < 7; jo++) {
            float e = expf(sc[jo] - mx);
            p[i][jo] = e;
            sum += e;
        }
        float inv = 1.0f / sum;
        #pragma unroll
        for (int jo = 0; jo < 7; jo++) p[i][jo] *= inv;
    }
    __syncthreads();
    for (int idx = tid; idx < 65 * 64; idx += 256) {
        int i = idx >> 6, d = idx & 63;
        float s = 0.f;
        #pragma unroll
        for (int jo = 0; jo < 7; jo++) {
            int j = i - 3 + jo;
            if (j >= 0 && j < 65) s += p[i][jo] * v[j][d];
        }
        int col = h * 64 + d;
        int pp = col >> 3, pos = col & 7;
        size_t rb = ((size_t)b * 65 + i) * 384;
        ushort hi = f2b(s);
        o[rb + pp * 16 + pos] = hi;
        o[rb + pp * 16 + 8 + pos] = f2b(s - b2f(hi));
    }
}

// ---------------- hyper head (fp32) ----------------
__global__ __launch_bounds__(128) void head_kernel(
    const float* __restrict__ cls, const float* __restrict__ hc_w,
    const float* __restrict__ hc_b, const float* __restrict__ head_w,
    const float* __restrict__ head_b, float* __restrict__ out)
{
    __shared__ float c[192];
    __shared__ float hh[384];
    int b = blockIdx.x, tid = threadIdx.x;
    for (int i = tid; i < 192; i += 128) c[i] = cls[(size_t)b * 192 + i];
    __syncthreads();
    for (int i = tid; i < 384; i += 128) {
        int k = i / 96, o = i % 96;
        float s = hc_b[i];
        #pragma unroll
        for (int j = 0; j < 4; j++) {
            int pp = (k - j + 4) & 3;
            const float* w = hc_w + ((size_t)pp * 96 + o) * 48;
            const float* xv = c + j * 48;
            #pragma unroll
            for (int cc = 0; cc < 48; cc++) s += xv[cc] * w[cc];
        }
        hh[i] = gelu_f(s);
    }
    __syncthreads();
    for (int i = tid; i < 100; i += 128) {
        float s = head_b[i];
        const float* w = head_w + (size_t)i * 384;
        for (int kk = 0; kk < 384; kk++) s += hh[kk] * w[kk];
        out[(size_t)b * 100 + i] = s;
    }
}

extern "C" void kernel_launch(void* const* d_in, const int* in_sizes, int n_in,
                              void* d_out, int out_size, void* d_ws, size_t ws_size,
                              hipStream_t stream)
{
    const float* x        = (const float*)d_in[0];
    const float* conv_w   = (const float*)d_in[1];
    const float* conv_b   = (const float*)d_in[2];
    const float* pe_g     = (const float*)d_in[3];
    const float* pe_b     = (const float*)d_in[4];
    const float* cls_tok  = (const float*)d_in[5];
    const float* pos      = (const float*)d_in[6];
    const float* n1_g     = (const float*)d_in[7];
    const float* n1_b     = (const float*)d_in[8];
    const float* qkv_w    = (const float*)d_in[9];
    const float* temp     = (const float*)d_in[10];
    const float* proj_w   = (const float*)d_in[11];
    const float* proj_b   = (const float*)d_in[12];
    const float* n2_g     = (const float*)d_in[13];
    const float* n2_b     = (const float*)d_in[14];
    const float* gate_w   = (const float*)d_in[15];
    const float* gate_b   = (const float*)d_in[16];
    const float* e_w1     = (const float*)d_in[17];
    const float* e_b1     = (const float*)d_in[18];
    const float* e_w2     = (const float*)d_in[19];
    const float* e_b2     = (const float*)d_in[20];
    const float* attn_sc  = (const float*)d_in[21];
    const float* mlp_sc   = (const float*)d_in[22];
    const float* norm_g   = (const float*)d_in[23];
    const float* norm_b   = (const float*)d_in[24];
    const float* hc_w     = (const float*)d_in[25];
    const float* hc_b     = (const float*)d_in[26];
    const float* head_w   = (const float*)d_in[27];
    const float* head_b   = (const float*)d_in[28];

    // ---- ws layout ----
    char* base = (char*)d_ws;
    float*  t    = (float*)base;   base += (size_t)ROWS * DD * 4;        // 6.39MB
    float*  gw   = (float*)base;   base += (size_t)ROWS * 4 * 4;         // 133KB
    float*  ycls = (float*)base;   base += (size_t)128 * DD * 4;         // 98KB
    ushort* ysp  = (ushort*)base;  base += (size_t)ROWS * 384 * 2;       // 6.39MB
    ushort* osp  = (ushort*)base;  base += (size_t)ROWS * 384 * 2;       // 6.39MB
    float*  qkvf = (float*)base;   base += (size_t)ROWS * 576 * 4;       // 19.2MB
    ushort* qkvw_sp = (ushort*)base; base += (size_t)12 * 576 * 384 * 2;   // 5.3MB
    ushort* projw_sp = (ushort*)base; base += (size_t)12 * 192 * 384 * 2;  // 1.8MB
    ushort* ew1_sp  = (ushort*)base; base += (size_t)12 * 1536 * 384 * 2;  // 14.2MB
    ushort* ew2_sp  = (ushort*)base; base += (size_t)12 * 192 * 3072 * 2;  // 14.2MB

    // ---- weight split-conversion ----
    {
        long np = (long)12 * 576 * 192 / 8;
        cvt_split_kernel<<<(int)((np + 255) / 256), 256, 0, stream>>>(qkv_w, qkvw_sp, np);
        np = (long)12 * 192 * 192 / 8;
        cvt_split_kernel<<<(int)((np + 255) / 256), 256, 0, stream>>>(proj_w, projw_sp, np);
        np = (long)12 * 1536 * 192 / 8;
        cvt_split_kernel<<<(int)((np + 255) / 256), 256, 0, stream>>>(e_w1, ew1_sp, np);
        long n = (long)12 * 192 * 192;
        permw2_kernel<<<(int)((n + 255) / 256), 256, 0, stream>>>(e_w2, ew2_sp);
    }

    embed_kernel<<<128 * 65, 192, 0, stream>>>(x, conv_w, conv_b, pe_g, pe_b, cls_tok, pos, t);

    for (int l = 0; l < 12; l++) {
        ln_kernel<<<ROWS, 192, 0, stream>>>(
            t, nullptr, ysp, n1_g + l * DD, n1_b + l * DD, DD, nullptr, nullptr, nullptr);
        mfma_gemm<0><<<dim3(130, 9), 256, 0, stream>>>(
            ysp, qkvw_sp + (size_t)l * 576 * 384, 576, 192, qkvf, nullptr, nullptr, nullptr);
        attn_kernel<<<128 * 3, 256, 0, stream>>>(qkvf, temp + l * 3, osp);
        mfma_gemm<2><<<dim3(130, 3), 256, 0, stream>>>(
            osp, projw_sp + (size_t)l * 192 * 384, 192, 192,
            nullptr, t, proj_b + l * DD, attn_sc + l);
        ln_kernel<<<ROWS, 192, 0, stream>>>(
            t, nullptr, ysp, n2_g + l * DD, n2_b + l * DD, DD,
            gate_w + (size_t)l * 4 * DD, gate_b + l * 4, gw);
        moe_kernel<<<260, 256, 0, stream>>>(
            ysp, ew1_sp + (size_t)l * 1536 * 384, ew2_sp + (size_t)l * 192 * 3072,
            e_b1 + (size_t)l * 1536, e_b2 + (size_t)l * 4 * 192, mlp_sc + l, gw, t);
    }

    ln_kernel<<<128, 192, 0, stream>>>(
        t, ycls, nullptr, norm_g, norm_b, (long)65 * DD, nullptr, nullptr, nullptr);
    head_kernel<<<128, 128, 0, stream>>>(ycls, hc_w, hc_b, head_w, head_b, (float*)d_out);
}

// Round 5
// 2009.474 us; speedup vs baseline: 1.0876x; 1.0876x over previous
//
#include <hip/hip_runtime.h>
#include <cmath>

// Shapes: B=128, D=192, DEPTH=12, H=3(hd=64), E=4, N=65(tokens), NC=100, WIN_HALF=3
#define ROWS 8320
#define DD   192

typedef __attribute__((ext_vector_type(8))) short bhalf8;
typedef __attribute__((ext_vector_type(4))) float floatx4;

#define GLD16(gp, lp) __builtin_amdgcn_global_load_lds( \
    (const __attribute__((address_space(1))) void*)(gp), \
    (__attribute__((address_space(3))) void*)(lp), 16, 0, 0)

#define MFMA_BF16 __builtin_amdgcn_mfma_f32_16x16x32_bf16

__device__ __forceinline__ float gelu_f(float x) {
    return 0.5f * x * (1.0f + erff(x * 0.70710678118654752440f));
}
__device__ __forceinline__ ushort f2b(float f) {
    unsigned u = __float_as_uint(f);
    unsigned r = (u + 0x7FFFu + ((u >> 16) & 1u)) >> 16;
    return (ushort)r;
}
__device__ __forceinline__ float b2f(ushort u) {
    return __uint_as_float(((unsigned)u) << 16);
}

// block-wide sum for blockDim.x == 192
__device__ __forceinline__ float blk_sum_192(float v, float* sbuf) {
    int tid = threadIdx.x;
    sbuf[tid] = v;
    __syncthreads();
    for (int off = 96; off >= 3; off >>= 1) {
        if (tid < off) sbuf[tid] += sbuf[tid + off];
        __syncthreads();
    }
    float r = sbuf[0] + sbuf[1] + sbuf[2];
    __syncthreads();
    return r;
}

// ---------------- weight split-convert: flat [rows*K] fp32 -> [pair][hi8|lo8] ----------------
__global__ __launch_bounds__(256) void cvt_split_kernel(
    const float* __restrict__ s, ushort* __restrict__ d, long npairs)
{
    long i = (long)blockIdx.x * 256 + threadIdx.x;
    if (i >= npairs) return;
    const float* sp = s + i * 8;
    ushort* dp = d + i * 16;
    #pragma unroll
    for (int j = 0; j < 8; j++) {
        float v = sp[j];
        ushort hi = f2b(v);
        float lo = v - b2f(hi);
        dp[j] = hi;
        dp[8 + j] = f2b(lo);
    }
}

// e_w2 (12,4,192,384) -> split-pair layout [l][n][K'=1536] with col = e*384+k
__global__ __launch_bounds__(256) void permw2_kernel(
    const float* __restrict__ s, ushort* __restrict__ d)
{
    long i = (long)blockIdx.x * 256 + threadIdx.x;   // (l, n, p), p in 0..191
    if (i >= (long)12 * 192 * 192) return;
    int l = (int)(i / (192 * 192));
    int rem = (int)(i % (192 * 192));
    int n = rem / 192, p = rem % 192;
    int c0 = p * 8;
    int e = c0 / 384, k0 = c0 % 384;
    const float* sp = s + (((size_t)l * 4 + e) * 192 + n) * 384 + k0;
    ushort* dp = d + i * 16;
    #pragma unroll
    for (int j = 0; j < 8; j++) {
        float v = sp[j];
        ushort hi = f2b(v);
        float lo = v - b2f(hi);
        dp[j] = hi;
        dp[8 + j] = f2b(lo);
    }
}

// ---------------- patch embed + LN + cls + pos (fp32) ----------------
__global__ __launch_bounds__(192) void embed_kernel(
    const float* __restrict__ x, const float* __restrict__ conv_w,
    const float* __restrict__ conv_b, const float* __restrict__ pe_g,
    const float* __restrict__ pe_b, const float* __restrict__ cls_tok,
    const float* __restrict__ pos, float* __restrict__ t)
{
    __shared__ float patch[48];
    __shared__ float red[192];
    int blk = blockIdx.x;
    int b = blk / 65, n = blk % 65;
    int tid = threadIdx.x;
    if (n == 0) {
        t[(size_t)b * 65 * DD + tid] = cls_tok[tid] + pos[tid];
        return;
    }
    int p = n - 1, gy = p / 8, gx = p % 8;
    if (tid < 48) {
        int c = tid / 16, iy = (tid % 16) / 4, ix = tid % 4;
        patch[tid] = x[((size_t)b * 3 + c) * 1024 + (size_t)(gy * 4 + iy) * 32 + (gx * 4 + ix)];
    }
    __syncthreads();
    float s = conv_b[tid];
    const float* w = conv_w + (size_t)tid * 48;
    #pragma unroll
    for (int f = 0; f < 48; f++) s += patch[f] * w[f];
    float mean = blk_sum_192(s, red) * (1.0f / 192.0f);
    float d = s - mean;
    float var = blk_sum_192(d * d, red) * (1.0f / 192.0f);
    float o = d * rsqrtf(var + 1e-5f) * pe_g[tid] + pe_b[tid];
    t[((size_t)b * 65 + n) * DD + tid] = o + pos[(size_t)n * DD + tid];
}

// ---------------- LayerNorm (+optional fused gate): fp32 in (strided) ----------------
__global__ __launch_bounds__(192) void ln_kernel(
    const float* __restrict__ in, float* __restrict__ yf, ushort* __restrict__ ysp,
    const float* __restrict__ g, const float* __restrict__ bb, long in_stride,
    const float* __restrict__ gwm, const float* __restrict__ gb,
    float* __restrict__ gwout)
{
    __shared__ float red[192];
    __shared__ float gp[3][4];
    int r = blockIdx.x, tid = threadIdx.x;
    float v = in[(size_t)r * in_stride + tid];
    float mean = blk_sum_192(v, red) * (1.0f / 192.0f);
    float d = v - mean;
    float var = blk_sum_192(d * d, red) * (1.0f / 192.0f);
    float o = d * rsqrtf(var + 1e-5f) * g[tid] + bb[tid];
    if (yf) yf[(size_t)r * DD + tid] = o;
    if (ysp) {
        int p = tid >> 3, pos = tid & 7;
        ushort hi = f2b(o);
        ysp[(size_t)r * 384 + p * 16 + pos] = hi;
        ysp[(size_t)r * 384 + p * 16 + 8 + pos] = f2b(o - b2f(hi));
    }
    if (gwm) {
        float p0 = o * gwm[tid], p1 = o * gwm[192 + tid];
        float p2 = o * gwm[384 + tid], p3 = o * gwm[576 + tid];
        #pragma unroll
        for (int off = 32; off > 0; off >>= 1) {
            p0 += __shfl_down(p0, off);
            p1 += __shfl_down(p1, off);
            p2 += __shfl_down(p2, off);
            p3 += __shfl_down(p3, off);
        }
        if ((tid & 63) == 0) {
            int w = tid >> 6;
            gp[w][0] = p0; gp[w][1] = p1; gp[w][2] = p2; gp[w][3] = p3;
        }
        __syncthreads();
        if (tid == 0) {
            float g4[4];
            #pragma unroll
            for (int e = 0; e < 4; e++) g4[e] = gp[0][e] + gp[1][e] + gp[2][e] + gb[e];
            float mx = fmaxf(fmaxf(g4[0], g4[1]), fmaxf(g4[2], g4[3]));
            float ex[4];
            #pragma unroll
            for (int e = 0; e < 4; e++) ex[e] = expf(g4[e] - mx);
            int i0 = 0;
            #pragma unroll
            for (int e = 1; e < 4; e++) if (ex[e] > ex[i0]) i0 = e;
            int i1 = (i0 == 0) ? 1 : 0;
            #pragma unroll
            for (int e = 0; e < 4; e++) if (e != i0 && ex[e] > ex[i1]) i1 = e;
            float denom = ex[i0] + ex[i1];
            float out[4] = {0.f, 0.f, 0.f, 0.f};
            out[i0] = ex[i0] / denom; out[i1] = ex[i1] / denom;
            #pragma unroll
            for (int e = 0; e < 4; e++) gwout[(size_t)r * 4 + e] = out[e];
        }
    }
}

// ---------------- split-bf16 MFMA GEMM (qkv / proj) ----------------
// MODE 0: qkv  -> outF fp32 [M][Nn]
// MODE 2: proj -> t[r*192+n] += scale[0]*(acc + bias[n])
template <int MODE>
__global__ __launch_bounds__(256) void mfma_gemm(
    const ushort* __restrict__ A, const ushort* __restrict__ W,
    int Nn, int Ktot,
    float* __restrict__ outF, float* __restrict__ t,
    const float* __restrict__ bias, const float* __restrict__ scale)
{
    __shared__ __align__(16) ushort As[64 * 192];   // 64 rows x 24 chunks(16B)
    __shared__ __align__(16) ushort Ws[64 * 192];
    const int tid = threadIdx.x;
    const int lane = tid & 63, wave = tid >> 6;
    const int m0 = blockIdx.x * 64, n0 = blockIdx.y * 64;
    const int wm = (wave & 1) * 32, wn = (wave >> 1) * 32;
    const int lr = lane & 15, quad = lane >> 4;

    floatx4 zero = {0.f, 0.f, 0.f, 0.f};
    floatx4 acc[2][2];
    acc[0][0] = zero; acc[0][1] = zero; acc[1][0] = zero; acc[1][1] = zero;

    const int nstage = Ktot / 96;
    const size_t rstride = (size_t)Ktot * 2;

    for (int st = 0; st < nstage; st++) {
        #pragma unroll
        for (int j = 0; j < 6; j++) {
            int sidx = (wave * 6 + j) * 64 + lane;
            int row = sidx / 24, c = sidx % 24;
            int gc = st * 24 + (c ^ (row & 7));
            GLD16(A + (size_t)(m0 + row) * rstride + gc * 8,
                  (char*)As + (size_t)(wave * 6 + j) * 1024);
            GLD16(W + (size_t)(n0 + row) * rstride + gc * 8,
                  (char*)Ws + (size_t)(wave * 6 + j) * 1024);
        }
        __syncthreads();
        #pragma unroll
        for (int m = 0; m < 3; m++) {
            int p = m * 4 + quad;
            bhalf8 ah[2], al[2], wh[2], wl[2];
            #pragma unroll
            for (int ti = 0; ti < 2; ti++) {
                int row = wm + ti * 16 + lr;
                ah[ti] = *(const bhalf8*)(As + (row * 24 + ((2 * p) ^ (row & 7))) * 8);
                al[ti] = *(const bhalf8*)(As + (row * 24 + ((2 * p + 1) ^ (row & 7))) * 8);
                int col = wn + ti * 16 + lr;
                wh[ti] = *(const bhalf8*)(Ws + (col * 24 + ((2 * p) ^ (col & 7))) * 8);
                wl[ti] = *(const bhalf8*)(Ws + (col * 24 + ((2 * p + 1) ^ (col & 7))) * 8);
            }
            #pragma unroll
            for (int ti = 0; ti < 2; ti++)
                #pragma unroll
                for (int tj = 0; tj < 2; tj++) {
                    acc[ti][tj] = MFMA_BF16(ah[ti], wh[tj], acc[ti][tj], 0, 0, 0);
                    acc[ti][tj] = MFMA_BF16(ah[ti], wl[tj], acc[ti][tj], 0, 0, 0);
                    acc[ti][tj] = MFMA_BF16(al[ti], wh[tj], acc[ti][tj], 0, 0, 0);
                }
        }
        __syncthreads();
    }

    float sc = (MODE == 2) ? scale[0] : 0.f;
    #pragma unroll
    for (int ti = 0; ti < 2; ti++)
        #pragma unroll
        for (int tj = 0; tj < 2; tj++)
            #pragma unroll
            for (int r = 0; r < 4; r++) {
                int grow = m0 + wm + ti * 16 + quad * 4 + r;
                int gcol = n0 + wn + tj * 16 + lr;
                float v = acc[ti][tj][r];
                if (MODE == 0) {
                    outF[(size_t)grow * Nn + gcol] = v;
                } else {
                    t[(size_t)grow * DD + gcol] += sc * (v + bias[gcol]);
                }
            }
}

// ---------------- fused MoE, expert-parallel ----------------
// grid (260, 4): block = 32 rows x expert e. 12 chunk-iters of 32 h-cols.
// t += atomically: mlp_sc * gw[r,e] * (gelu(y@w1_e^T+b1_e)@w2_e^T + b2_e)
// (gate weight folded into h in the gelu epilogue; b2 term added at the end)
__global__ __launch_bounds__(256) void moe_kernel(
    const ushort* __restrict__ ysp, const ushort* __restrict__ w1,
    const ushort* __restrict__ w2, const float* __restrict__ b1,
    const float* __restrict__ b2, const float* __restrict__ scale,
    const float* __restrict__ gw, float* __restrict__ t)
{
    __shared__ __align__(16) ushort As[32 * 384];   // 32 rows x 48 chunks  (24KB)
    __shared__ __align__(16) ushort W1s[32 * 384];  // 32 h-cols x 48 chunks (24KB)
    __shared__ __align__(16) ushort W2s[192 * 64];  // 192 cols x 8 chunks   (24KB)
    __shared__ __align__(16) ushort Hs[32 * 64];    // 32 rows x 8 chunks    (4KB)
    const int tid = threadIdx.x;
    const int lane = tid & 63, wave = tid >> 6;
    const int lr = lane & 15, quad = lane >> 4;
    const int r0 = blockIdx.x * 32;
    const int e  = blockIdx.y;
    const int wr = (wave & 1) * 16;        // row tile base (both gemms)
    const int wc1 = (wave >> 1) * 16;      // gemm1 col base (h cols 0..31)
    const int wc2 = (wave >> 1) * 96;      // gemm2 col base (out cols 0..191)

    // stage A (ysp rows r0..r0+31, full K=192 split = 48 chunks)
    #pragma unroll
    for (int i = 0; i < 6; i++) {
        int s = (wave * 6 + i) * 64 + lane;
        int rr = s / 48, c = s % 48;
        GLD16(ysp + (size_t)(r0 + rr) * 384 + (c ^ (rr & 7)) * 8, (char*)As + s * 16);
    }
    // stage W1[e][chunk 0]
    #pragma unroll
    for (int i = 0; i < 6; i++) {
        int s = (wave * 6 + i) * 64 + lane;
        int rr = s / 48, c = s % 48;
        GLD16(w1 + (size_t)(384 * e + rr) * 384 + (c ^ (rr & 7)) * 8, (char*)W1s + s * 16);
    }
    __syncthreads();

    floatx4 zero = {0.f, 0.f, 0.f, 0.f};
    floatx4 acc2[6];
    #pragma unroll
    for (int j = 0; j < 6; j++) acc2[j] = zero;

    for (int nc = 0; nc < 12; nc++) {
        int ncg = e * 12 + nc;            // global h-chunk index (into b1 / w2 cols)
        // issue W2[ncg] loads (fly during gemm1)
        #pragma unroll
        for (int i = 0; i < 6; i++) {
            int s = (wave * 6 + i) * 64 + lane;
            int n = s >> 3, c = s & 7;
            GLD16(w2 + (size_t)n * 3072 + (8 * ncg + (c ^ (n & 7))) * 8, (char*)W2s + s * 16);
        }
        // gemm1: h_chunk[32][32], this wave computes 16x16 tile (wr, wc1)
        floatx4 acc1 = zero;
        #pragma unroll
        for (int m = 0; m < 6; m++) {
            int ch = 8 * m + 2 * quad;
            int ar = wr + lr;
            bhalf8 ah = *(const bhalf8*)(As + ((size_t)ar * 48 + (ch ^ (ar & 7))) * 8);
            bhalf8 al = *(const bhalf8*)(As + ((size_t)ar * 48 + ((ch + 1) ^ (ar & 7))) * 8);
            int cr = wc1 + lr;
            bhalf8 wh = *(const bhalf8*)(W1s + ((size_t)cr * 48 + (ch ^ (cr & 7))) * 8);
            bhalf8 wl = *(const bhalf8*)(W1s + ((size_t)cr * 48 + ((ch + 1) ^ (cr & 7))) * 8);
            acc1 = MFMA_BF16(ah, wh, acc1, 0, 0, 0);
            acc1 = MFMA_BF16(ah, wl, acc1, 0, 0, 0);
            acc1 = MFMA_BF16(al, wh, acc1, 0, 0, 0);
        }
        // epilogue: gelu + gate weight -> Hs (split-pair, XOR-swizzled)
        #pragma unroll
        for (int r = 0; r < 4; r++) {
            int hrow = wr + quad * 4 + r;
            int hcol = wc1 + lr;
            float v = acc1[r] + b1[32 * ncg + hcol];
            v = gelu_f(v) * gw[(size_t)(r0 + hrow) * 4 + e];
            int p = hcol >> 3, pos = hcol & 7;
            ushort hi = f2b(v);
            Hs[((size_t)hrow * 8 + ((2 * p) ^ (hrow & 7))) * 8 + pos] = hi;
            Hs[((size_t)hrow * 8 + ((2 * p + 1) ^ (hrow & 7))) * 8 + pos] = f2b(v - b2f(hi));
        }
        __syncthreads();   // W2 loaded (vmcnt drain), Hs visible, W1 reads done
        if (nc < 11) {     // prefetch W1[nc+1] during gemm2
            int nn = nc + 1;
            #pragma unroll
            for (int i = 0; i < 6; i++) {
                int s = (wave * 6 + i) * 64 + lane;
                int rr = s / 48, c = s % 48;
                GLD16(w1 + (size_t)(384 * e + 32 * nn + rr) * 384 + (c ^ (rr & 7)) * 8,
                      (char*)W1s + s * 16);
            }
        }
        // gemm2: out[32][192] partial, K=32; wave tiles rows wr, cols wc2+tj*16
        {
            int ch = 2 * quad;
            int ar = wr + lr;
            bhalf8 ah = *(const bhalf8*)(Hs + ((size_t)ar * 8 + (ch ^ (ar & 7))) * 8);
            bhalf8 al = *(const bhalf8*)(Hs + ((size_t)ar * 8 + ((ch + 1) ^ (ar & 7))) * 8);
            #pragma unroll
            for (int tj = 0; tj < 6; tj++) {
                int cr = wc2 + tj * 16 + lr;
                bhalf8 wh = *(const bhalf8*)(W2s + ((size_t)cr * 8 + (ch ^ (cr & 7))) * 8);
                bhalf8 wl = *(const bhalf8*)(W2s + ((size_t)cr * 8 + ((ch + 1) ^ (cr & 7))) * 8);
                acc2[tj] = MFMA_BF16(ah, wh, acc2[tj], 0, 0, 0);
                acc2[tj] = MFMA_BF16(ah, wl, acc2[tj], 0, 0, 0);
                acc2[tj] = MFMA_BF16(al, wh, acc2[tj], 0, 0, 0);
            }
        }
        __syncthreads();   // W1[nc+1] ready; W2s/Hs reads done before overwrite
    }

    float sc = scale[0];
    #pragma unroll
    for (int tj = 0; tj < 6; tj++) {
        int gcol = wc2 + tj * 16 + lr;
        #pragma unroll
        for (int r = 0; r < 4; r++) {
            int grow = r0 + wr + quad * 4 + r;
            float add = sc * (acc2[tj][r] + gw[(size_t)grow * 4 + e] * b2[e * 192 + gcol]);
            atomicAdd(&t[(size_t)grow * DD + gcol], add);
        }
    }
}

// ---------------- banded attention: fp32 qkv in, split-pair o out ----------------
__global__ __launch_bounds__(256) void attn_kernel(
    const float* __restrict__ qkv, const float* __restrict__ temp,
    ushort* __restrict__ o)
{
    __shared__ float q[65][64], k[65][64], v[65][64];
    __shared__ float p[65][8];
    int bh = blockIdx.x;
    int b = bh / 3, h = bh % 3;
    int tid = threadIdx.x;
    float coef = 0.125f / temp[h];
    const float* base = qkv + (size_t)b * 65 * 576 + h * 64;
    for (int idx = tid; idx < 65 * 64; idx += 256) {
        int i = idx >> 6, d = idx & 63;
        q[i][d] = base[(size_t)i * 576 + d];
        k[i][d] = base[(size_t)i * 576 + 192 + d];
        v[i][d] = base[(size_t)i * 576 + 384 + d];
    }
    __syncthreads();
    if (tid < 65) {
        int i = tid;
        float sc[7];
        float mx = -1e30f;
        #pragma unroll
        for (int jo = 0; jo < 7; jo++) {
            int j = i - 3 + jo;
            if (j >= 0 && j < 65) {
                float s = 0.f;
                #pragma unroll
                for (int d = 0; d < 64; d++) s += q[i][d] * k[j][d];
                sc[jo] = s * coef;
                mx = fmaxf(mx, sc[jo]);
            } else sc[jo] = -1e30f;
        }
        float sum = 0.f;
        #pragma unroll
        for (int jo = 0; jo < 7; jo++) {
            float e = expf(sc[jo] - mx);
            p[i][jo] = e;
            sum += e;
        }
        float inv = 1.0f / sum;
        #pragma unroll
        for (int jo = 0; jo < 7; jo++) p[i][jo] *= inv;
    }
    __syncthreads();
    for (int idx = tid; idx < 65 * 64; idx += 256) {
        int i = idx >> 6, d = idx & 63;
        float s = 0.f;
        #pragma unroll
        for (int jo = 0; jo < 7; jo++) {
            int j = i - 3 + jo;
            if (j >= 0 && j < 65) s += p[i][jo] * v[j][d];
        }
        int col = h * 64 + d;
        int pp = col >> 3, pos = col & 7;
        size_t rb = ((size_t)b * 65 + i) * 384;
        ushort hi = f2b(s);
        o[rb + pp * 16 + pos] = hi;
        o[rb + pp * 16 + 8 + pos] = f2b(s - b2f(hi));
    }
}

// ---------------- hyper head (fp32) ----------------
__global__ __launch_bounds__(128) void head_kernel(
    const float* __restrict__ cls, const float* __restrict__ hc_w,
    const float* __restrict__ hc_b, const float* __restrict__ head_w,
    const float* __restrict__ head_b, float* __restrict__ out)
{
    __shared__ float c[192];
    __shared__ float hh[384];
    int b = blockIdx.x, tid = threadIdx.x;
    for (int i = tid; i < 192; i += 128) c[i] = cls[(size_t)b * 192 + i];
    __syncthreads();
    for (int i = tid; i < 384; i += 128) {
        int k = i / 96, o = i % 96;
        float s = hc_b[i];
        #pragma unroll
        for (int j = 0; j < 4; j++) {
            int pp = (k - j + 4) & 3;
            const float* w = hc_w + ((size_t)pp * 96 + o) * 48;
            const float* xv = c + j * 48;
            #pragma unroll
            for (int cc = 0; cc < 48; cc++) s += xv[cc] * w[cc];
        }
        hh[i] = gelu_f(s);
    }
    __syncthreads();
    for (int i = tid; i < 100; i += 128) {
        float s = head_b[i];
        const float* w = head_w + (size_t)i * 384;
        for (int kk = 0; kk < 384; kk++) s += hh[kk] * w[kk];
        out[(size_t)b * 100 + i] = s;
    }
}

extern "C" void kernel_launch(void* const* d_in, const int* in_sizes, int n_in,
                              void* d_out, int out_size, void* d_ws, size_t ws_size,
                              hipStream_t stream)
{
    const float* x        = (const float*)d_in[0];
    const float* conv_w   = (const float*)d_in[1];
    const float* conv_b   = (const float*)d_in[2];
    const float* pe_g     = (const float*)d_in[3];
    const float* pe_b     = (const float*)d_in[4];
    const float* cls_tok  = (const float*)d_in[5];
    const float* pos      = (const float*)d_in[6];
    const float* n1_g     = (const float*)d_in[7];
    const float* n1_b     = (const float*)d_in[8];
    const float* qkv_w    = (const float*)d_in[9];
    const float* temp     = (const float*)d_in[10];
    const float* proj_w   = (const float*)d_in[11];
    const float* proj_b   = (const float*)d_in[12];
    const float* n2_g     = (const float*)d_in[13];
    const float* n2_b     = (const float*)d_in[14];
    const float* gate_w   = (const float*)d_in[15];
    const float* gate_b   = (const float*)d_in[16];
    const float* e_w1     = (const float*)d_in[17];
    const float* e_b1     = (const float*)d_in[18];
    const float* e_w2     = (const float*)d_in[19];
    const float* e_b2     = (const float*)d_in[20];
    const float* attn_sc  = (const float*)d_in[21];
    const float* mlp_sc   = (const float*)d_in[22];
    const float* norm_g   = (const float*)d_in[23];
    const float* norm_b   = (const float*)d_in[24];
    const float* hc_w     = (const float*)d_in[25];
    const float* hc_b     = (const float*)d_in[26];
    const float* head_w   = (const float*)d_in[27];
    const float* head_b   = (const float*)d_in[28];

    // ---- ws layout ----
    char* base = (char*)d_ws;
    float*  t    = (float*)base;   base += (size_t)ROWS * DD * 4;        // 6.39MB
    float*  gw   = (float*)base;   base += (size_t)ROWS * 4 * 4;         // 133KB
    float*  ycls = (float*)base;   base += (size_t)128 * DD * 4;         // 98KB
    ushort* ysp  = (ushort*)base;  base += (size_t)ROWS * 384 * 2;       // 6.39MB
    ushort* osp  = (ushort*)base;  base += (size_t)ROWS * 384 * 2;       // 6.39MB
    float*  qkvf = (float*)base;   base += (size_t)ROWS * 576 * 4;       // 19.2MB
    ushort* qkvw_sp = (ushort*)base; base += (size_t)12 * 576 * 384 * 2;   // 5.3MB
    ushort* projw_sp = (ushort*)base; base += (size_t)12 * 192 * 384 * 2;  // 1.8MB
    ushort* ew1_sp  = (ushort*)base; base += (size_t)12 * 1536 * 384 * 2;  // 14.2MB
    ushort* ew2_sp  = (ushort*)base; base += (size_t)12 * 192 * 3072 * 2;  // 14.2MB

    // ---- weight split-conversion ----
    {
        long np = (long)12 * 576 * 192 / 8;
        cvt_split_kernel<<<(int)((np + 255) / 256), 256, 0, stream>>>(qkv_w, qkvw_sp, np);
        np = (long)12 * 192 * 192 / 8;
        cvt_split_kernel<<<(int)((np + 255) / 256), 256, 0, stream>>>(proj_w, projw_sp, np);
        np = (long)12 * 1536 * 192 / 8;
        cvt_split_kernel<<<(int)((np + 255) / 256), 256, 0, stream>>>(e_w1, ew1_sp, np);
        long n = (long)12 * 192 * 192;
        permw2_kernel<<<(int)((n + 255) / 256), 256, 0, stream>>>(e_w2, ew2_sp);
    }

    embed_kernel<<<128 * 65, 192, 0, stream>>>(x, conv_w, conv_b, pe_g, pe_b, cls_tok, pos, t);

    for (int l = 0; l < 12; l++) {
        ln_kernel<<<ROWS, 192, 0, stream>>>(
            t, nullptr, ysp, n1_g + l * DD, n1_b + l * DD, DD, nullptr, nullptr, nullptr);
        mfma_gemm<0><<<dim3(130, 9), 256, 0, stream>>>(
            ysp, qkvw_sp + (size_t)l * 576 * 384, 576, 192, qkvf, nullptr, nullptr, nullptr);
        attn_kernel<<<128 * 3, 256, 0, stream>>>(qkvf, temp + l * 3, osp);
        mfma_gemm<2><<<dim3(130, 3), 256, 0, stream>>>(
            osp, projw_sp + (size_t)l * 192 * 384, 192, 192,
            nullptr, t, proj_b + l * DD, attn_sc + l);
        ln_kernel<<<ROWS, 192, 0, stream>>>(
            t, nullptr, ysp, n2_g + l * DD, n2_b + l * DD, DD,
            gate_w + (size_t)l * 4 * DD, gate_b + l * 4, gw);
        moe_kernel<<<dim3(260, 4), 256, 0, stream>>>(
            ysp, ew1_sp + (size_t)l * 1536 * 384, ew2_sp + (size_t)l * 192 * 3072,
            e_b1 + (size_t)l * 1536, e_b2 + (size_t)l * 4 * 192, mlp_sc + l, gw, t);
    }

    ln_kernel<<<128, 192, 0, stream>>>(
        t, ycls, nullptr, norm_g, norm_b, (long)65 * DD, nullptr, nullptr, nullptr);
    head_kernel<<<128, 128, 0, stream>>>(ycls, hc_w, hc_b, head_w, head_b, (float*)d_out);
}

// Round 6
// 1865.670 us; speedup vs baseline: 1.1714x; 1.0771x over previous
//
#include <hip/hip_runtime.h>
#include <cmath>

// Shapes: B=128, D=192, DEPTH=12, H=3(hd=64), E=4, N=65(tokens), NC=100, WIN_HALF=3
#define ROWS 8320
#define DD   192

typedef __attribute__((ext_vector_type(8))) short bhalf8;
typedef __attribute__((ext_vector_type(4))) float floatx4;

#define GLD16(gp, lp) __builtin_amdgcn_global_load_lds( \
    (const __attribute__((address_space(1))) void*)(gp), \
    (__attribute__((address_space(3))) void*)(lp), 16, 0, 0)

#define MFMA_BF16 __builtin_amdgcn_mfma_f32_16x16x32_bf16

__device__ __forceinline__ float gelu_f(float x) {
    return 0.5f * x * (1.0f + erff(x * 0.70710678118654752440f));
}
__device__ __forceinline__ ushort f2b(float f) {
    unsigned u = __float_as_uint(f);
    unsigned r = (u + 0x7FFFu + ((u >> 16) & 1u)) >> 16;
    return (ushort)r;
}
__device__ __forceinline__ float b2f(ushort u) {
    return __uint_as_float(((unsigned)u) << 16);
}

// block-wide sum for blockDim.x == 192
__device__ __forceinline__ float blk_sum_192(float v, float* sbuf) {
    int tid = threadIdx.x;
    sbuf[tid] = v;
    __syncthreads();
    for (int off = 96; off >= 3; off >>= 1) {
        if (tid < off) sbuf[tid] += sbuf[tid + off];
        __syncthreads();
    }
    float r = sbuf[0] + sbuf[1] + sbuf[2];
    __syncthreads();
    return r;
}

// ---------------- weight split-convert: flat [rows*K] fp32 -> [pair][hi8|lo8] ----------------
__global__ __launch_bounds__(256) void cvt_split_kernel(
    const float* __restrict__ s, ushort* __restrict__ d, long npairs)
{
    long i = (long)blockIdx.x * 256 + threadIdx.x;
    if (i >= npairs) return;
    const float* sp = s + i * 8;
    ushort* dp = d + i * 16;
    #pragma unroll
    for (int j = 0; j < 8; j++) {
        float v = sp[j];
        ushort hi = f2b(v);
        float lo = v - b2f(hi);
        dp[j] = hi;
        dp[8 + j] = f2b(lo);
    }
}

// e_w2 (12,4,192,384) -> split-pair layout [l][n][K'=1536] with col = e*384+k
__global__ __launch_bounds__(256) void permw2_kernel(
    const float* __restrict__ s, ushort* __restrict__ d)
{
    long i = (long)blockIdx.x * 256 + threadIdx.x;   // (l, n, p), p in 0..191
    if (i >= (long)12 * 192 * 192) return;
    int l = (int)(i / (192 * 192));
    int rem = (int)(i % (192 * 192));
    int n = rem / 192, p = rem % 192;
    int c0 = p * 8;
    int e = c0 / 384, k0 = c0 % 384;
    const float* sp = s + (((size_t)l * 4 + e) * 192 + n) * 384 + k0;
    ushort* dp = d + i * 16;
    #pragma unroll
    for (int j = 0; j < 8; j++) {
        float v = sp[j];
        ushort hi = f2b(v);
        float lo = v - b2f(hi);
        dp[j] = hi;
        dp[8 + j] = f2b(lo);
    }
}

// ---------------- patch embed + LN + cls + pos (fp32) ----------------
__global__ __launch_bounds__(192) void embed_kernel(
    const float* __restrict__ x, const float* __restrict__ conv_w,
    const float* __restrict__ conv_b, const float* __restrict__ pe_g,
    const float* __restrict__ pe_b, const float* __restrict__ cls_tok,
    const float* __restrict__ pos, float* __restrict__ t)
{
    __shared__ float patch[48];
    __shared__ float red[192];
    int blk = blockIdx.x;
    int b = blk / 65, n = blk % 65;
    int tid = threadIdx.x;
    if (n == 0) {
        t[(size_t)b * 65 * DD + tid] = cls_tok[tid] + pos[tid];
        return;
    }
    int p = n - 1, gy = p / 8, gx = p % 8;
    if (tid < 48) {
        int c = tid / 16, iy = (tid % 16) / 4, ix = tid % 4;
        patch[tid] = x[((size_t)b * 3 + c) * 1024 + (size_t)(gy * 4 + iy) * 32 + (gx * 4 + ix)];
    }
    __syncthreads();
    float s = conv_b[tid];
    const float* w = conv_w + (size_t)tid * 48;
    #pragma unroll
    for (int f = 0; f < 48; f++) s += patch[f] * w[f];
    float mean = blk_sum_192(s, red) * (1.0f / 192.0f);
    float d = s - mean;
    float var = blk_sum_192(d * d, red) * (1.0f / 192.0f);
    float o = d * rsqrtf(var + 1e-5f) * pe_g[tid] + pe_b[tid];
    t[((size_t)b * 65 + n) * DD + tid] = o + pos[(size_t)n * DD + tid];
}

// ---------------- LayerNorm (+optional fused gate top2): fp32 in (strided) ----------------
// gate result per row: int4 {e0, e1, bits(w0), bits(w1)}
__global__ __launch_bounds__(192) void ln_kernel(
    const float* __restrict__ in, float* __restrict__ yf, ushort* __restrict__ ysp,
    const float* __restrict__ g, const float* __restrict__ bb, long in_stride,
    const float* __restrict__ gwm, const float* __restrict__ gb,
    int4* __restrict__ gwout)
{
    __shared__ float red[192];
    __shared__ float gp[3][4];
    int r = blockIdx.x, tid = threadIdx.x;
    float v = in[(size_t)r * in_stride + tid];
    float mean = blk_sum_192(v, red) * (1.0f / 192.0f);
    float d = v - mean;
    float var = blk_sum_192(d * d, red) * (1.0f / 192.0f);
    float o = d * rsqrtf(var + 1e-5f) * g[tid] + bb[tid];
    if (yf) yf[(size_t)r * DD + tid] = o;
    if (ysp) {
        int p = tid >> 3, pos = tid & 7;
        ushort hi = f2b(o);
        ysp[(size_t)r * 384 + p * 16 + pos] = hi;
        ysp[(size_t)r * 384 + p * 16 + 8 + pos] = f2b(o - b2f(hi));
    }
    if (gwm) {
        float p0 = o * gwm[tid], p1 = o * gwm[192 + tid];
        float p2 = o * gwm[384 + tid], p3 = o * gwm[576 + tid];
        #pragma unroll
        for (int off = 32; off > 0; off >>= 1) {
            p0 += __shfl_down(p0, off);
            p1 += __shfl_down(p1, off);
            p2 += __shfl_down(p2, off);
            p3 += __shfl_down(p3, off);
        }
        if ((tid & 63) == 0) {
            int w = tid >> 6;
            gp[w][0] = p0; gp[w][1] = p1; gp[w][2] = p2; gp[w][3] = p3;
        }
        __syncthreads();
        if (tid == 0) {
            float g4[4];
            #pragma unroll
            for (int e = 0; e < 4; e++) g4[e] = gp[0][e] + gp[1][e] + gp[2][e] + gb[e];
            float mx = fmaxf(fmaxf(g4[0], g4[1]), fmaxf(g4[2], g4[3]));
            float ex[4];
            #pragma unroll
            for (int e = 0; e < 4; e++) ex[e] = expf(g4[e] - mx);
            int i0 = 0;
            #pragma unroll
            for (int e = 1; e < 4; e++) if (ex[e] > ex[i0]) i0 = e;
            int i1 = (i0 == 0) ? 1 : 0;
            #pragma unroll
            for (int e = 0; e < 4; e++) if (e != i0 && ex[e] > ex[i1]) i1 = e;
            float denom = ex[i0] + ex[i1];
            int4 o4;
            o4.x = i0; o4.y = i1;
            o4.z = __float_as_int(ex[i0] / denom);
            o4.w = __float_as_int(ex[i1] / denom);
            gwout[r] = o4;
        }
    }
}

// ---------------- build per-expert row lists (ballot-aggregated appends) ----------------
__global__ __launch_bounds__(256) void gate_build_kernel(
    const int4* __restrict__ gwrow, int* __restrict__ cnt,
    int* __restrict__ list, float* __restrict__ wlist, int rows)
{
    int r = blockIdx.x * 256 + threadIdx.x;
    int lane = threadIdx.x & 63;
    bool active = r < rows;
    int4 gv = active ? gwrow[r] : int4{-1, -1, 0, 0};
    #pragma unroll
    for (int e = 0; e < 4; e++) {
        bool sel = active && (gv.x == e || gv.y == e);
        float w = (gv.x == e) ? __int_as_float(gv.z) : __int_as_float(gv.w);
        unsigned long long mask = __ballot(sel);
        int cw = __popcll(mask);
        if (cw) {
            int leader = __ffsll((long long)mask) - 1;
            int base = 0;
            if (lane == leader) base = atomicAdd(&cnt[e], cw);
            base = __shfl(base, leader);
            if (sel) {
                int idx = base + __popcll(mask & ((1ULL << lane) - 1ULL));
                list[(size_t)e * ROWS + idx] = r;
                wlist[(size_t)e * ROWS + idx] = w;
            }
        }
    }
}

// ---------------- split-bf16 MFMA GEMM (qkv / proj) ----------------
// MODE 0: qkv  -> outF fp32 [M][Nn]
// MODE 2: proj -> t[r*192+n] += scale[0]*(acc + bias[n])
template <int MODE>
__global__ __launch_bounds__(256) void mfma_gemm(
    const ushort* __restrict__ A, const ushort* __restrict__ W,
    int Nn, int Ktot,
    float* __restrict__ outF, float* __restrict__ t,
    const float* __restrict__ bias, const float* __restrict__ scale)
{
    __shared__ __align__(16) ushort As[64 * 192];   // 64 rows x 24 chunks(16B)
    __shared__ __align__(16) ushort Ws[64 * 192];
    const int tid = threadIdx.x;
    const int lane = tid & 63, wave = tid >> 6;
    const int m0 = blockIdx.x * 64, n0 = blockIdx.y * 64;
    const int wm = (wave & 1) * 32, wn = (wave >> 1) * 32;
    const int lr = lane & 15, quad = lane >> 4;

    floatx4 zero = {0.f, 0.f, 0.f, 0.f};
    floatx4 acc[2][2];
    acc[0][0] = zero; acc[0][1] = zero; acc[1][0] = zero; acc[1][1] = zero;

    const int nstage = Ktot / 96;
    const size_t rstride = (size_t)Ktot * 2;

    for (int st = 0; st < nstage; st++) {
        #pragma unroll
        for (int j = 0; j < 6; j++) {
            int sidx = (wave * 6 + j) * 64 + lane;
            int row = sidx / 24, c = sidx % 24;
            int gc = st * 24 + (c ^ (row & 7));
            GLD16(A + (size_t)(m0 + row) * rstride + gc * 8,
                  (char*)As + (size_t)(wave * 6 + j) * 1024);
            GLD16(W + (size_t)(n0 + row) * rstride + gc * 8,
                  (char*)Ws + (size_t)(wave * 6 + j) * 1024);
        }
        __syncthreads();
        #pragma unroll
        for (int m = 0; m < 3; m++) {
            int p = m * 4 + quad;
            bhalf8 ah[2], al[2], wh[2], wl[2];
            #pragma unroll
            for (int ti = 0; ti < 2; ti++) {
                int row = wm + ti * 16 + lr;
                ah[ti] = *(const bhalf8*)(As + (row * 24 + ((2 * p) ^ (row & 7))) * 8);
                al[ti] = *(const bhalf8*)(As + (row * 24 + ((2 * p + 1) ^ (row & 7))) * 8);
                int col = wn + ti * 16 + lr;
                wh[ti] = *(const bhalf8*)(Ws + (col * 24 + ((2 * p) ^ (col & 7))) * 8);
                wl[ti] = *(const bhalf8*)(Ws + (col * 24 + ((2 * p + 1) ^ (col & 7))) * 8);
            }
            #pragma unroll
            for (int ti = 0; ti < 2; ti++)
                #pragma unroll
                for (int tj = 0; tj < 2; tj++) {
                    acc[ti][tj] = MFMA_BF16(ah[ti], wh[tj], acc[ti][tj], 0, 0, 0);
                    acc[ti][tj] = MFMA_BF16(ah[ti], wl[tj], acc[ti][tj], 0, 0, 0);
                    acc[ti][tj] = MFMA_BF16(al[ti], wh[tj], acc[ti][tj], 0, 0, 0);
                }
        }
        __syncthreads();
    }

    float sc = (MODE == 2) ? scale[0] : 0.f;
    #pragma unroll
    for (int ti = 0; ti < 2; ti++)
        #pragma unroll
        for (int tj = 0; tj < 2; tj++)
            #pragma unroll
            for (int r = 0; r < 4; r++) {
                int grow = m0 + wm + ti * 16 + quad * 4 + r;
                int gcol = n0 + wn + tj * 16 + lr;
                float v = acc[ti][tj][r];
                if (MODE == 0) {
                    outF[(size_t)grow * Nn + gcol] = v;
                } else {
                    t[(size_t)grow * DD + gcol] += sc * (v + bias[gcol]);
                }
            }
}

// ---------------- fused MoE, expert-parallel + row-gather (top-2 sparse) ----------------
// grid (260, 4): block = 32 gathered rows of expert e's list. Early-exits past cnt[e].
// t[row] += atomically: mlp_sc * w * (gelu(y_row@w1_e^T+b1_e)@w2_e^T + b2_e), w from wlist.
__global__ __launch_bounds__(256) void moe_kernel(
    const ushort* __restrict__ ysp, const ushort* __restrict__ w1,
    const ushort* __restrict__ w2, const float* __restrict__ b1,
    const float* __restrict__ b2, const float* __restrict__ scale,
    const int* __restrict__ cnt, const int* __restrict__ list,
    const float* __restrict__ wlist, float* __restrict__ t)
{
    __shared__ __align__(16) ushort As[32 * 384];   // 32 rows x 48 chunks  (24KB)
    __shared__ __align__(16) ushort W1s[32 * 384];  // 32 h-cols x 48 chunks (24KB)
    __shared__ __align__(16) ushort W2s[192 * 64];  // 192 cols x 8 chunks   (24KB)
    __shared__ __align__(16) ushort Hs[32 * 64];    // 32 rows x 8 chunks    (4KB)
    __shared__ int   rl[32];
    __shared__ float wl[32];
    const int e  = blockIdx.y;
    const int cnte = cnt[e];
    const int r0 = blockIdx.x * 32;
    if (r0 >= cnte) return;
    const int tid = threadIdx.x;
    const int lane = tid & 63, wave = tid >> 6;
    const int lr = lane & 15, quad = lane >> 4;
    const int wr = (wave & 1) * 16;        // row tile base (both gemms)
    const int wc1 = (wave >> 1) * 16;      // gemm1 col base (h cols 0..31)
    const int wc2 = (wave >> 1) * 96;      // gemm2 col base (out cols 0..191)

    if (tid < 32) {
        int sl = r0 + tid;
        bool ok = sl < cnte;
        rl[tid] = ok ? list[(size_t)e * ROWS + sl] : 0;
        wl[tid] = ok ? wlist[(size_t)e * ROWS + sl] : 0.f;
    }
    __syncthreads();

    // stage A (gathered rows, full K=192 split = 48 chunks each)
    #pragma unroll
    for (int i = 0; i < 6; i++) {
        int s = (wave * 6 + i) * 64 + lane;
        int rr = s / 48, c = s % 48;
        GLD16(ysp + (size_t)rl[rr] * 384 + (c ^ (rr & 7)) * 8, (char*)As + s * 16);
    }
    // stage W1[e][chunk 0]
    #pragma unroll
    for (int i = 0; i < 6; i++) {
        int s = (wave * 6 + i) * 64 + lane;
        int rr = s / 48, c = s % 48;
        GLD16(w1 + (size_t)(384 * e + rr) * 384 + (c ^ (rr & 7)) * 8, (char*)W1s + s * 16);
    }
    __syncthreads();

    floatx4 zero = {0.f, 0.f, 0.f, 0.f};
    floatx4 acc2[6];
    #pragma unroll
    for (int j = 0; j < 6; j++) acc2[j] = zero;

    for (int nc = 0; nc < 12; nc++) {
        int ncg = e * 12 + nc;            // global h-chunk index (into b1 / w2 cols)
        // issue W2[ncg] loads (fly during gemm1)
        #pragma unroll
        for (int i = 0; i < 6; i++) {
            int s = (wave * 6 + i) * 64 + lane;
            int n = s >> 3, c = s & 7;
            GLD16(w2 + (size_t)n * 3072 + (8 * ncg + (c ^ (n & 7))) * 8, (char*)W2s + s * 16);
        }
        // gemm1: h_chunk[32][32], this wave computes 16x16 tile (wr, wc1)
        floatx4 acc1 = zero;
        #pragma unroll
        for (int m = 0; m < 6; m++) {
            int ch = 8 * m + 2 * quad;
            int ar = wr + lr;
            bhalf8 ah = *(const bhalf8*)(As + ((size_t)ar * 48 + (ch ^ (ar & 7))) * 8);
            bhalf8 al = *(const bhalf8*)(As + ((size_t)ar * 48 + ((ch + 1) ^ (ar & 7))) * 8);
            int cr = wc1 + lr;
            bhalf8 wh = *(const bhalf8*)(W1s + ((size_t)cr * 48 + (ch ^ (cr & 7))) * 8);
            bhalf8 wlo = *(const bhalf8*)(W1s + ((size_t)cr * 48 + ((ch + 1) ^ (cr & 7))) * 8);
            acc1 = MFMA_BF16(ah, wh, acc1, 0, 0, 0);
            acc1 = MFMA_BF16(ah, wlo, acc1, 0, 0, 0);
            acc1 = MFMA_BF16(al, wh, acc1, 0, 0, 0);
        }
        // epilogue: gelu*w -> Hs, packed 32-bit writes (lane pairs via shfl_xor)
        #pragma unroll
        for (int r = 0; r < 4; r++) {
            int hrow = wr + quad * 4 + r;
            int hcol = wc1 + lr;
            float v = gelu_f(acc1[r] + b1[32 * ncg + hcol]) * wl[hrow];
            float vp = __shfl_xor(v, 1);
            float a = ((lr & 1) == 0) ? v : vp;    // value at even col
            float b = ((lr & 1) == 0) ? vp : v;    // value at odd col
            ushort ha = f2b(a), hb = f2b(b);
            int p = hcol >> 3;
            int basepos = (hcol & 7) & ~1;
            unsigned word;
            int chunk;
            if ((lr & 1) == 0) {                   // even lane: hi chunk
                word = (unsigned)ha | ((unsigned)hb << 16);
                chunk = (2 * p) ^ (hrow & 7);
            } else {                               // odd lane: lo chunk
                float la = a - b2f(ha), lb = b - b2f(hb);
                word = (unsigned)f2b(la) | ((unsigned)f2b(lb) << 16);
                chunk = (2 * p + 1) ^ (hrow & 7);
            }
            *(unsigned*)(Hs + (size_t)(hrow * 8 + chunk) * 8 + basepos) = word;
        }
        __syncthreads();   // W2 loaded (vmcnt drain), Hs visible, W1 reads done
        if (nc < 11) {     // prefetch W1[nc+1] during gemm2
            int nn = nc + 1;
            #pragma unroll
            for (int i = 0; i < 6; i++) {
                int s = (wave * 6 + i) * 64 + lane;
                int rr = s / 48, c = s % 48;
                GLD16(w1 + (size_t)(384 * e + 32 * nn + rr) * 384 + (c ^ (rr & 7)) * 8,
                      (char*)W1s + s * 16);
            }
        }
        // gemm2: out[32][192] partial, K=32; wave tiles rows wr, cols wc2+tj*16
        {
            int ch = 2 * quad;
            int ar = wr + lr;
            bhalf8 ah = *(const bhalf8*)(Hs + ((size_t)ar * 8 + (ch ^ (ar & 7))) * 8);
            bhalf8 al = *(const bhalf8*)(Hs + ((size_t)ar * 8 + ((ch + 1) ^ (ar & 7))) * 8);
            #pragma unroll
            for (int tj = 0; tj < 6; tj++) {
                int cr = wc2 + tj * 16 + lr;
                bhalf8 wh = *(const bhalf8*)(W2s + ((size_t)cr * 8 + (ch ^ (cr & 7))) * 8);
                bhalf8 wlo = *(const bhalf8*)(W2s + ((size_t)cr * 8 + ((ch + 1) ^ (cr & 7))) * 8);
                acc2[tj] = MFMA_BF16(ah, wh, acc2[tj], 0, 0, 0);
                acc2[tj] = MFMA_BF16(ah, wlo, acc2[tj], 0, 0, 0);
                acc2[tj] = MFMA_BF16(al, wh, acc2[tj], 0, 0, 0);
            }
        }
        __syncthreads();   // W1[nc+1] ready; W2s/Hs reads done before overwrite
    }

    float sc = scale[0];
    #pragma unroll
    for (int tj = 0; tj < 6; tj++) {
        int gcol = wc2 + tj * 16 + lr;
        #pragma unroll
        for (int r = 0; r < 4; r++) {
            int lrow = wr + quad * 4 + r;
            float add = sc * (acc2[tj][r] + wl[lrow] * b2[e * 192 + gcol]);
            atomicAdd(&t[(size_t)rl[lrow] * DD + gcol], add);
        }
    }
}

// ---------------- banded attention: fp32 qkv in, split-pair o out ----------------
__global__ __launch_bounds__(256) void attn_kernel(
    const float* __restrict__ qkv, const float* __restrict__ temp,
    ushort* __restrict__ o)
{
    __shared__ float q[65][64], k[65][64], v[65][64];
    __shared__ float p[65][8];
    int bh = blockIdx.x;
    int b = bh / 3, h = bh % 3;
    int tid = threadIdx.x;
    float coef = 0.125f / temp[h];
    const float* base = qkv + (size_t)b * 65 * 576 + h * 64;
    for (int idx = tid; idx < 65 * 64; idx += 256) {
        int i = idx >> 6, d = idx & 63;
        q[i][d] = base[(size_t)i * 576 + d];
        k[i][d] = base[(size_t)i * 576 + 192 + d];
        v[i][d] = base[(size_t)i * 576 + 384 + d];
    }
    __syncthreads();
    if (tid < 65) {
        int i = tid;
        float sc[7];
        float mx = -1e30f;
        #pragma unroll
        for (int jo = 0; jo < 7; jo++) {
            int j = i - 3 + jo;
            if (j >= 0 && j < 65) {
                float s = 0.f;
                #pragma unroll
                for (int d = 0; d < 64; d++) s += q[i][d] * k[j][d];
                sc[jo] = s * coef;
                mx = fmaxf(mx, sc[jo]);
            } else sc[jo] = -1e30f;
        }
        float sum = 0.f;
        #pragma unroll
        for (int jo = 0; jo < 7; jo++) {
            float e = expf(sc[jo] - mx);
            p[i][jo] = e;
            sum += e;
        }
        float inv = 1.0f / sum;
        #pragma unroll
        for (int jo = 0; jo < 7; jo++) p[i][jo] *= inv;
    }
    __syncthreads();
    for (int idx = tid; idx < 65 * 64; idx += 256) {
        int i = idx >> 6, d = idx & 63;
        float s = 0.f;
        #pragma unroll
        for (int jo = 0; jo < 7; jo++) {
            int j = i - 3 + jo;
            if (j >= 0 && j < 65) s += p[i][jo] * v[j][d];
        }
        int col = h * 64 + d;
        int pp = col >> 3, pos = col & 7;
        size_t rb = ((size_t)b * 65 + i) * 384;
        ushort hi = f2b(s);
        o[rb + pp * 16 + pos] = hi;
        o[rb + pp * 16 + 8 + pos] = f2b(s - b2f(hi));
    }
}

// ---------------- hyper head (fp32) ----------------
__global__ __launch_bounds__(128) void head_kernel(
    const float* __restrict__ cls, const float* __restrict__ hc_w,
    const float* __restrict__ hc_b, const float* __restrict__ head_w,
    const float* __restrict__ head_b, float* __restrict__ out)
{
    __shared__ float c[192];
    __shared__ float hh[384];
    int b = blockIdx.x, tid = threadIdx.x;
    for (int i = tid; i < 192; i += 128) c[i] = cls[(size_t)b * 192 + i];
    __syncthreads();
    for (int i = tid; i < 384; i += 128) {
        int k = i / 96, o = i % 96;
        float s = hc_b[i];
        #pragma unroll
        for (int j = 0; j < 4; j++) {
            int pp = (k - j + 4) & 3;
            const float* w = hc_w + ((size_t)pp * 96 + o) * 48;
            const float* xv = c + j * 48;
            #pragma unroll
            for (int cc = 0; cc < 48; cc++) s += xv[cc] * w[cc];
        }
        hh[i] = gelu_f(s);
    }
    __syncthreads();
    for (int i = tid; i < 100; i += 128) {
        float s = head_b[i];
        const float* w = head_w + (size_t)i * 384;
        for (int kk = 0; kk < 384; kk++) s += hh[kk] * w[kk];
        out[(size_t)b * 100 + i] = s;
    }
}

extern "C" void kernel_launch(void* const* d_in, const int* in_sizes, int n_in,
                              void* d_out, int out_size, void* d_ws, size_t ws_size,
                              hipStream_t stream)
{
    const float* x        = (const float*)d_in[0];
    const float* conv_w   = (const float*)d_in[1];
    const float* conv_b   = (const float*)d_in[2];
    const float* pe_g     = (const float*)d_in[3];
    const float* pe_b     = (const float*)d_in[4];
    const float* cls_tok  = (const float*)d_in[5];
    const float* pos      = (const float*)d_in[6];
    const float* n1_g     = (const float*)d_in[7];
    const float* n1_b     = (const float*)d_in[8];
    const float* qkv_w    = (const float*)d_in[9];
    const float* temp     = (const float*)d_in[10];
    const float* proj_w   = (const float*)d_in[11];
    const float* proj_b   = (const float*)d_in[12];
    const float* n2_g     = (const float*)d_in[13];
    const float* n2_b     = (const float*)d_in[14];
    const float* gate_w   = (const float*)d_in[15];
    const float* gate_b   = (const float*)d_in[16];
    const float* e_w1     = (const float*)d_in[17];
    const float* e_b1     = (const float*)d_in[18];
    const float* e_w2     = (const float*)d_in[19];
    const float* e_b2     = (const float*)d_in[20];
    const float* attn_sc  = (const float*)d_in[21];
    const float* mlp_sc   = (const float*)d_in[22];
    const float* norm_g   = (const float*)d_in[23];
    const float* norm_b   = (const float*)d_in[24];
    const float* hc_w     = (const float*)d_in[25];
    const float* hc_b     = (const float*)d_in[26];
    const float* head_w   = (const float*)d_in[27];
    const float* head_b   = (const float*)d_in[28];

    // ---- ws layout ----
    char* base = (char*)d_ws;
    float*  t     = (float*)base;   base += (size_t)ROWS * DD * 4;        // 6.39MB
    int4*   gwrow = (int4*)base;    base += (size_t)ROWS * 16;            // 133KB
    int*    cnts  = (int*)base;     base += (size_t)12 * 4 * sizeof(int); // 192B
    int*    elist = (int*)base;     base += (size_t)4 * ROWS * 4;         // 133KB
    float*  ewls  = (float*)base;   base += (size_t)4 * ROWS * 4;         // 133KB
    float*  ycls  = (float*)base;   base += (size_t)128 * DD * 4;         // 98KB
    ushort* ysp   = (ushort*)base;  base += (size_t)ROWS * 384 * 2;       // 6.39MB
    ushort* osp   = (ushort*)base;  base += (size_t)ROWS * 384 * 2;       // 6.39MB
    float*  qkvf  = (float*)base;   base += (size_t)ROWS * 576 * 4;       // 19.2MB
    ushort* qkvw_sp = (ushort*)base; base += (size_t)12 * 576 * 384 * 2;   // 5.3MB
    ushort* projw_sp = (ushort*)base; base += (size_t)12 * 192 * 384 * 2;  // 1.8MB
    ushort* ew1_sp  = (ushort*)base; base += (size_t)12 * 1536 * 384 * 2;  // 14.2MB
    ushort* ew2_sp  = (ushort*)base; base += (size_t)12 * 192 * 3072 * 2;  // 14.2MB

    hipMemsetAsync(cnts, 0, 12 * 4 * sizeof(int), stream);

    // ---- weight split-conversion ----
    {
        long np = (long)12 * 576 * 192 / 8;
        cvt_split_kernel<<<(int)((np + 255) / 256), 256, 0, stream>>>(qkv_w, qkvw_sp, np);
        np = (long)12 * 192 * 192 / 8;
        cvt_split_kernel<<<(int)((np + 255) / 256), 256, 0, stream>>>(proj_w, projw_sp, np);
        np = (long)12 * 1536 * 192 / 8;
        cvt_split_kernel<<<(int)((np + 255) / 256), 256, 0, stream>>>(e_w1, ew1_sp, np);
        long n = (long)12 * 192 * 192;
        permw2_kernel<<<(int)((n + 255) / 256), 256, 0, stream>>>(e_w2, ew2_sp);
    }

    embed_kernel<<<128 * 65, 192, 0, stream>>>(x, conv_w, conv_b, pe_g, pe_b, cls_tok, pos, t);

    for (int l = 0; l < 12; l++) {
        ln_kernel<<<ROWS, 192, 0, stream>>>(
            t, nullptr, ysp, n1_g + l * DD, n1_b + l * DD, DD, nullptr, nullptr, nullptr);
        mfma_gemm<0><<<dim3(130, 9), 256, 0, stream>>>(
            ysp, qkvw_sp + (size_t)l * 576 * 384, 576, 192, qkvf, nullptr, nullptr, nullptr);
        attn_kernel<<<128 * 3, 256, 0, stream>>>(qkvf, temp + l * 3, osp);
        mfma_gemm<2><<<dim3(130, 3), 256, 0, stream>>>(
            osp, projw_sp + (size_t)l * 192 * 384, 192, 192,
            nullptr, t, proj_b + l * DD, attn_sc + l);
        ln_kernel<<<ROWS, 192, 0, stream>>>(
            t, nullptr, ysp, n2_g + l * DD, n2_b + l * DD, DD,
            gate_w + (size_t)l * 4 * DD, gate_b + l * 4, gwrow);
        gate_build_kernel<<<(ROWS + 255) / 256, 256, 0, stream>>>(
            gwrow, cnts + l * 4, elist, ewls, ROWS);
        moe_kernel<<<dim3(260, 4), 256, 0, stream>>>(
            ysp, ew1_sp + (size_t)l * 1536 * 384, ew2_sp + (size_t)l * 192 * 3072,
            e_b1 + (size_t)l * 1536, e_b2 + (size_t)l * 4 * 192, mlp_sc + l,
            cnts + l * 4, elist, ewls, t);
    }

    ln_kernel<<<128, 192, 0, stream>>>(
        t, ycls, nullptr, norm_g, norm_b, (long)65 * DD, nullptr, nullptr, nullptr);
    head_kernel<<<128, 128, 0, stream>>>(ycls, hc_w, hc_b, head_w, head_b, (float*)d_out);
}

// Round 7
// 1463.943 us; speedup vs baseline: 1.4928x; 1.2744x over previous
//
#include <hip/hip_runtime.h>
#include <cmath>

// Shapes: B=128, D=192, DEPTH=12, H=3(hd=64), E=4, N=65(tokens), NC=100, WIN_HALF=3
#define ROWS 8320
#define DD   192

typedef __attribute__((ext_vector_type(8))) short bhalf8;
typedef __attribute__((ext_vector_type(8))) _Float16 half8;
typedef __attribute__((ext_vector_type(4))) float floatx4;

#define GLD16(gp, lp) __builtin_amdgcn_global_load_lds( \
    (const __attribute__((address_space(1))) void*)(gp), \
    (__attribute__((address_space(3))) void*)(lp), 16, 0, 0)

#define MFMA_BF16 __builtin_amdgcn_mfma_f32_16x16x32_bf16
#define MFMA_F16  __builtin_amdgcn_mfma_f32_16x16x32_f16

__device__ __forceinline__ float gelu_f(float x) {
    return 0.5f * x * (1.0f + erff(x * 0.70710678118654752440f));
}
__device__ __forceinline__ ushort f2b(float f) {
    unsigned u = __float_as_uint(f);
    unsigned r = (u + 0x7FFFu + ((u >> 16) & 1u)) >> 16;
    return (ushort)r;
}
__device__ __forceinline__ float b2f(ushort u) {
    return __uint_as_float(((unsigned)u) << 16);
}

// block-wide sum for blockDim.x == 192 (embed only)
__device__ __forceinline__ float blk_sum_192(float v, float* sbuf) {
    int tid = threadIdx.x;
    sbuf[tid] = v;
    __syncthreads();
    for (int off = 96; off >= 3; off >>= 1) {
        if (tid < off) sbuf[tid] += sbuf[tid + off];
        __syncthreads();
    }
    float r = sbuf[0] + sbuf[1] + sbuf[2];
    __syncthreads();
    return r;
}

// ---------------- weight split-convert: flat fp32 -> [pair][hi8|lo8] ----------------
__global__ __launch_bounds__(256) void cvt_split_kernel(
    const float* __restrict__ s, ushort* __restrict__ d, long npairs)
{
    long i = (long)blockIdx.x * 256 + threadIdx.x;
    if (i >= npairs) return;
    const float* sp = s + i * 8;
    ushort* dp = d + i * 16;
    #pragma unroll
    for (int j = 0; j < 8; j++) {
        float v = sp[j];
        ushort hi = f2b(v);
        float lo = v - b2f(hi);
        dp[j] = hi;
        dp[8 + j] = f2b(lo);
    }
}

// flat fp32 -> fp16
__global__ __launch_bounds__(256) void cvt_h_kernel(
    const float* __restrict__ s, _Float16* __restrict__ d, long n8)
{
    long i = (long)blockIdx.x * 256 + threadIdx.x;
    if (i >= n8) return;
    const float* sp = s + i * 8;
    _Float16* dp = d + i * 8;
    #pragma unroll
    for (int j = 0; j < 8; j++) dp[j] = (_Float16)sp[j];
}

// e_w2 (12,4,192,384) -> fp16 cat layout [l][n][K'=1536] with col = e*384+k
__global__ __launch_bounds__(256) void permw2h_kernel(
    const float* __restrict__ s, _Float16* __restrict__ d)
{
    long i = (long)blockIdx.x * 256 + threadIdx.x;   // (l, n, p), p in 0..191
    if (i >= (long)12 * 192 * 192) return;
    int l = (int)(i / (192 * 192));
    int rem = (int)(i % (192 * 192));
    int n = rem / 192, p = rem % 192;
    int c0 = p * 8;
    int e = c0 / 384, k0 = c0 % 384;
    const float* sp = s + (((size_t)l * 4 + e) * 192 + n) * 384 + k0;
    _Float16* dp = d + i * 8;
    #pragma unroll
    for (int j = 0; j < 8; j++) dp[j] = (_Float16)sp[j];
}

// ---------------- patch embed + LN + cls + pos (fp32) ----------------
__global__ __launch_bounds__(192) void embed_kernel(
    const float* __restrict__ x, const float* __restrict__ conv_w,
    const float* __restrict__ conv_b, const float* __restrict__ pe_g,
    const float* __restrict__ pe_b, const float* __restrict__ cls_tok,
    const float* __restrict__ pos, float* __restrict__ t)
{
    __shared__ float patch[48];
    __shared__ float red[192];
    int blk = blockIdx.x;
    int b = blk / 65, n = blk % 65;
    int tid = threadIdx.x;
    if (n == 0) {
        t[(size_t)b * 65 * DD + tid] = cls_tok[tid] + pos[tid];
        return;
    }
    int p = n - 1, gy = p / 8, gx = p % 8;
    if (tid < 48) {
        int c = tid / 16, iy = (tid % 16) / 4, ix = tid % 4;
        patch[tid] = x[((size_t)b * 3 + c) * 1024 + (size_t)(gy * 4 + iy) * 32 + (gx * 4 + ix)];
    }
    __syncthreads();
    float s = conv_b[tid];
    const float* w = conv_w + (size_t)tid * 48;
    #pragma unroll
    for (int f = 0; f < 48; f++) s += patch[f] * w[f];
    float mean = blk_sum_192(s, red) * (1.0f / 192.0f);
    float d = s - mean;
    float var = blk_sum_192(d * d, red) * (1.0f / 192.0f);
    float o = d * rsqrtf(var + 1e-5f) * pe_g[tid] + pe_b[tid];
    t[((size_t)b * 65 + n) * DD + tid] = o + pos[(size_t)n * DD + tid];
}

// ---------------- LayerNorm, wave-per-row (4 rows/block, shuffle-only) ----------------
// outputs (each optional): yf fp32, ysp split-bf16-pair, yh fp16;
// fused gate: softmax(y@gwm^T+gb) top2 -> gwout int4 {e0,e1,bits(w0),bits(w1)}
__global__ __launch_bounds__(256) void ln_kernel(
    const float* __restrict__ in, float* __restrict__ yf, ushort* __restrict__ ysp,
    _Float16* __restrict__ yh,
    const float* __restrict__ g, const float* __restrict__ bb, long in_stride, int nrows,
    const float* __restrict__ gwm, const float* __restrict__ gb,
    int4* __restrict__ gwout)
{
    int wave = threadIdx.x >> 6, lane = threadIdx.x & 63;
    int r = blockIdx.x * 4 + wave;
    if (r >= nrows) return;
    const float* row = in + (size_t)r * in_stride;
    float v0 = row[lane], v1 = row[lane + 64], v2 = row[lane + 128];
    float s = v0 + v1 + v2;
    #pragma unroll
    for (int off = 32; off > 0; off >>= 1) s += __shfl_xor(s, off);
    float mean = s * (1.0f / 192.0f);
    float d0 = v0 - mean, d1 = v1 - mean, d2 = v2 - mean;
    float q = d0 * d0 + d1 * d1 + d2 * d2;
    #pragma unroll
    for (int off = 32; off > 0; off >>= 1) q += __shfl_xor(q, off);
    float rstd = rsqrtf(q * (1.0f / 192.0f) + 1e-5f);
    float o0 = d0 * rstd * g[lane] + bb[lane];
    float o1 = d1 * rstd * g[lane + 64] + bb[lane + 64];
    float o2 = d2 * rstd * g[lane + 128] + bb[lane + 128];
    if (yf) {
        float* yr = yf + (size_t)r * DD;
        yr[lane] = o0; yr[lane + 64] = o1; yr[lane + 128] = o2;
    }
    if (ysp) {
        ushort* yr = ysp + (size_t)r * 384;
        #pragma unroll
        for (int j = 0; j < 3; j++) {
            int col = lane + j * 64;
            float o = (j == 0) ? o0 : (j == 1) ? o1 : o2;
            int p = col >> 3, pos = col & 7;
            ushort hi = f2b(o);
            yr[p * 16 + pos] = hi;
            yr[p * 16 + 8 + pos] = f2b(o - b2f(hi));
        }
    }
    if (yh) {
        _Float16* yr = yh + (size_t)r * DD;
        yr[lane] = (_Float16)o0; yr[lane + 64] = (_Float16)o1; yr[lane + 128] = (_Float16)o2;
    }
    if (gwm) {
        float pe[4];
        #pragma unroll
        for (int e = 0; e < 4; e++) {
            const float* w = gwm + (size_t)e * DD;
            pe[e] = o0 * w[lane] + o1 * w[lane + 64] + o2 * w[lane + 128];
            #pragma unroll
            for (int off = 32; off > 0; off >>= 1) pe[e] += __shfl_xor(pe[e], off);
        }
        if (lane == 0) {
            #pragma unroll
            for (int e = 0; e < 4; e++) pe[e] += gb[e];
            float mx = fmaxf(fmaxf(pe[0], pe[1]), fmaxf(pe[2], pe[3]));
            float ex[4];
            #pragma unroll
            for (int e = 0; e < 4; e++) ex[e] = expf(pe[e] - mx);
            int i0 = 0;
            #pragma unroll
            for (int e = 1; e < 4; e++) if (ex[e] > ex[i0]) i0 = e;
            int i1 = (i0 == 0) ? 1 : 0;
            #pragma unroll
            for (int e = 0; e < 4; e++) if (e != i0 && ex[e] > ex[i1]) i1 = e;
            float denom = ex[i0] + ex[i1];
            int4 o4;
            o4.x = i0; o4.y = i1;
            o4.z = __float_as_int(ex[i0] / denom);
            o4.w = __float_as_int(ex[i1] / denom);
            gwout[r] = o4;
        }
    }
}

// ---------------- build per-expert row lists (ballot-aggregated appends) ----------------
__global__ __launch_bounds__(256) void gate_build_kernel(
    const int4* __restrict__ gwrow, int* __restrict__ cnt,
    int* __restrict__ list, float* __restrict__ wlist, int rows)
{
    int r = blockIdx.x * 256 + threadIdx.x;
    int lane = threadIdx.x & 63;
    bool active = r < rows;
    int4 gv = active ? gwrow[r] : int4{-1, -1, 0, 0};
    #pragma unroll
    for (int e = 0; e < 4; e++) {
        bool sel = active && (gv.x == e || gv.y == e);
        float w = (gv.x == e) ? __int_as_float(gv.z) : __int_as_float(gv.w);
        unsigned long long mask = __ballot(sel);
        int cw = __popcll(mask);
        if (cw) {
            int leader = __ffsll((long long)mask) - 1;
            int base = 0;
            if (lane == leader) base = atomicAdd(&cnt[e], cw);
            base = __shfl(base, leader);
            if (sel) {
                int idx = base + __popcll(mask & ((1ULL << lane) - 1ULL));
                list[(size_t)e * ROWS + idx] = r;
                wlist[(size_t)e * ROWS + idx] = w;
            }
        }
    }
}

// ---------------- split-bf16 MFMA GEMM (qkv / proj) ----------------
// MODE 0: qkv  -> outF fp32 [M][Nn]
// MODE 2: proj -> t[r*192+n] += scale[0]*(acc + bias[n])
template <int MODE>
__global__ __launch_bounds__(256) void mfma_gemm(
    const ushort* __restrict__ A, const ushort* __restrict__ W,
    int Nn, int Ktot,
    float* __restrict__ outF, float* __restrict__ t,
    const float* __restrict__ bias, const float* __restrict__ scale)
{
    __shared__ __align__(16) ushort As[64 * 192];   // 64 rows x 24 chunks(16B)
    __shared__ __align__(16) ushort Ws[64 * 192];
    const int tid = threadIdx.x;
    const int lane = tid & 63, wave = tid >> 6;
    const int m0 = blockIdx.x * 64, n0 = blockIdx.y * 64;
    const int wm = (wave & 1) * 32, wn = (wave >> 1) * 32;
    const int lr = lane & 15, quad = lane >> 4;

    floatx4 zero = {0.f, 0.f, 0.f, 0.f};
    floatx4 acc[2][2];
    acc[0][0] = zero; acc[0][1] = zero; acc[1][0] = zero; acc[1][1] = zero;

    const int nstage = Ktot / 96;
    const size_t rstride = (size_t)Ktot * 2;

    for (int st = 0; st < nstage; st++) {
        #pragma unroll
        for (int j = 0; j < 6; j++) {
            int sidx = (wave * 6 + j) * 64 + lane;
            int row = sidx / 24, c = sidx % 24;
            int gc = st * 24 + (c ^ (row & 7));
            GLD16(A + (size_t)(m0 + row) * rstride + gc * 8,
                  (char*)As + (size_t)(wave * 6 + j) * 1024);
            GLD16(W + (size_t)(n0 + row) * rstride + gc * 8,
                  (char*)Ws + (size_t)(wave * 6 + j) * 1024);
        }
        __syncthreads();
        #pragma unroll
        for (int m = 0; m < 3; m++) {
            int p = m * 4 + quad;
            bhalf8 ah[2], al[2], wh[2], wl[2];
            #pragma unroll
            for (int ti = 0; ti < 2; ti++) {
                int row = wm + ti * 16 + lr;
                ah[ti] = *(const bhalf8*)(As + (row * 24 + ((2 * p) ^ (row & 7))) * 8);
                al[ti] = *(const bhalf8*)(As + (row * 24 + ((2 * p + 1) ^ (row & 7))) * 8);
                int col = wn + ti * 16 + lr;
                wh[ti] = *(const bhalf8*)(Ws + (col * 24 + ((2 * p) ^ (col & 7))) * 8);
                wl[ti] = *(const bhalf8*)(Ws + (col * 24 + ((2 * p + 1) ^ (col & 7))) * 8);
            }
            #pragma unroll
            for (int ti = 0; ti < 2; ti++)
                #pragma unroll
                for (int tj = 0; tj < 2; tj++) {
                    acc[ti][tj] = MFMA_BF16(ah[ti], wh[tj], acc[ti][tj], 0, 0, 0);
                    acc[ti][tj] = MFMA_BF16(ah[ti], wl[tj], acc[ti][tj], 0, 0, 0);
                    acc[ti][tj] = MFMA_BF16(al[ti], wh[tj], acc[ti][tj], 0, 0, 0);
                }
        }
        __syncthreads();
    }

    float sc = (MODE == 2) ? scale[0] : 0.f;
    #pragma unroll
    for (int ti = 0; ti < 2; ti++)
        #pragma unroll
        for (int tj = 0; tj < 2; tj++)
            #pragma unroll
            for (int r = 0; r < 4; r++) {
                int grow = m0 + wm + ti * 16 + quad * 4 + r;
                int gcol = n0 + wn + tj * 16 + lr;
                float v = acc[ti][tj][r];
                if (MODE == 0) {
                    outF[(size_t)grow * Nn + gcol] = v;
                } else {
                    t[(size_t)grow * DD + gcol] += sc * (v + bias[gcol]);
                }
            }
}

// ---------------- fused MoE v3: fp16 single-product, expert-parallel row-gather ----------------
// grid (260, 4): block = 32 gathered rows of expert e. 6 iters of 64 h-cols.
// t[row] += atomic: mlp_sc * w * (gelu(y@w1_e^T+b1_e)@w2_e^T + b2_e)
__global__ __launch_bounds__(256) void moe_kernel(
    const _Float16* __restrict__ yh, const _Float16* __restrict__ w1,
    const _Float16* __restrict__ w2, const float* __restrict__ b1,
    const float* __restrict__ b2, const float* __restrict__ scale,
    const int* __restrict__ cnt, const int* __restrict__ list,
    const float* __restrict__ wlist, float* __restrict__ t)
{
    __shared__ __align__(16) _Float16 As[32 * 192];   // 32 rows x 24 chunks (12KB)
    __shared__ __align__(16) _Float16 W1s[64 * 192];  // 64 hcols x 24 chunks (24KB)
    __shared__ __align__(16) _Float16 W2s[192 * 64];  // 192 cols x 8 chunks (24KB)
    __shared__ __align__(16) _Float16 Hs[32 * 64];    // 32 rows x 8 chunks (4KB)
    __shared__ int   rl[32];
    __shared__ float wl[32];
    const int e  = blockIdx.y;
    const int cnte = cnt[e];
    const int r0 = blockIdx.x * 32;
    if (r0 >= cnte) return;
    const int tid = threadIdx.x;
    const int lane = tid & 63, wave = tid >> 6;
    const int lr = lane & 15, quad = lane >> 4;
    const int wr = (wave & 1) * 16;        // row tile base (both gemms)
    const int wc1 = (wave >> 1) * 16;      // gemm1 col base within 64 (+ tc*32)
    const int wc2 = (wave >> 1) * 96;      // gemm2 col base (out cols 0..191)

    if (tid < 32) {
        int sl = r0 + tid;
        bool ok = sl < cnte;
        rl[tid] = ok ? list[(size_t)e * ROWS + sl] : 0;
        wl[tid] = ok ? wlist[(size_t)e * ROWS + sl] : 0.f;
    }
    __syncthreads();

    // stage A: 768 slots (3/thread), gathered rows, K=192 = 24 chunks
    #pragma unroll
    for (int i = 0; i < 3; i++) {
        int s = (wave * 3 + i) * 64 + lane;
        int rr = s / 24, c = s % 24;
        GLD16(yh + (size_t)rl[rr] * 192 + (c ^ (rr & 7)) * 8, (char*)As + s * 16);
    }
    // stage W1 chunk0: 1536 slots (6/thread), 64 hcols x 24 chunks
    #pragma unroll
    for (int i = 0; i < 6; i++) {
        int s = (wave * 6 + i) * 64 + lane;
        int rr = s / 24, c = s % 24;
        GLD16(w1 + ((size_t)e * 384 + rr) * 192 + (c ^ (rr & 7)) * 8, (char*)W1s + s * 16);
    }
    __syncthreads();

    floatx4 zero = {0.f, 0.f, 0.f, 0.f};
    floatx4 acc2[6];
    #pragma unroll
    for (int j = 0; j < 6; j++) acc2[j] = zero;

    for (int nc = 0; nc < 6; nc++) {
        int ncg = e * 6 + nc;             // global 64-col h-chunk index
        // issue W2[ncg] loads: 192 cols x 8 chunks = 1536 slots (fly during gemm1)
        #pragma unroll
        for (int i = 0; i < 6; i++) {
            int s = (wave * 6 + i) * 64 + lane;
            int n = s >> 3, c = s & 7;
            GLD16(w2 + (size_t)n * 1536 + (ncg * 8 + (c ^ (n & 7))) * 8, (char*)W2s + s * 16);
        }
        // gemm1: 32 rows x 64 hcols; wave: rows wr, cols wc1 + tc*32
        floatx4 acc1[2];
        acc1[0] = zero; acc1[1] = zero;
        #pragma unroll
        for (int m = 0; m < 6; m++) {
            int ar = wr + lr;
            int ch = m * 4 + quad;
            half8 a = *(const half8*)(As + ((size_t)ar * 24 + (ch ^ (ar & 7))) * 8);
            #pragma unroll
            for (int tc = 0; tc < 2; tc++) {
                int cr = wc1 + tc * 32 + lr;
                half8 w = *(const half8*)(W1s + ((size_t)cr * 24 + (ch ^ (cr & 7))) * 8);
                acc1[tc] = MFMA_F16(a, w, acc1[tc], 0, 0, 0);
            }
        }
        // epilogue: gelu*w -> Hs fp16, packed 32-bit writes (lane pairs)
        #pragma unroll
        for (int tc = 0; tc < 2; tc++)
            #pragma unroll
            for (int r = 0; r < 4; r++) {
                int hrow = wr + quad * 4 + r;
                int hcol = wc1 + tc * 32 + lr;
                float v = gelu_f(acc1[tc][r] + b1[64 * ncg + hcol]) * wl[hrow];
                float vp = __shfl_xor(v, 1);
                if ((lane & 1) == 0) {
                    union { _Float16 h[2]; unsigned u; } pk;
                    pk.h[0] = (_Float16)v;
                    pk.h[1] = (_Float16)vp;
                    int cl = (hcol >> 3) ^ (hrow & 7);
                    *(unsigned*)(Hs + ((size_t)hrow * 8 + cl) * 8 + (hcol & 7)) = pk.u;
                }
            }
        __syncthreads();   // W2+Hs ready, W1s reads done
        if (nc < 5) {      // prefetch W1[nc+1] during gemm2
            #pragma unroll
            for (int i = 0; i < 6; i++) {
                int s = (wave * 6 + i) * 64 + lane;
                int rr = s / 24, c = s % 24;
                GLD16(w1 + ((size_t)e * 384 + (nc + 1) * 64 + rr) * 192 + (c ^ (rr & 7)) * 8,
                      (char*)W1s + s * 16);
            }
        }
        // gemm2: out[32][192] partial, K=64; wave rows wr, cols wc2 + tj*16
        #pragma unroll
        for (int kk = 0; kk < 2; kk++) {
            int ar = wr + lr;
            int ch = kk * 4 + quad;
            half8 a = *(const half8*)(Hs + ((size_t)ar * 8 + (ch ^ (ar & 7))) * 8);
            #pragma unroll
            for (int tj = 0; tj < 6; tj++) {
                int cr = wc2 + tj * 16 + lr;
                half8 w = *(const half8*)(W2s + ((size_t)cr * 8 + (ch ^ (cr & 7))) * 8);
                acc2[tj] = MFMA_F16(a, w, acc2[tj], 0, 0, 0);
            }
        }
        __syncthreads();   // W1[nc+1] landed; W2s/Hs reads done before overwrite
    }

    float sc = scale[0];
    #pragma unroll
    for (int tj = 0; tj < 6; tj++) {
        int gcol = wc2 + tj * 16 + lr;
        #pragma unroll
        for (int r = 0; r < 4; r++) {
            int lrow = wr + quad * 4 + r;
            float add = sc * (acc2[tj][r] + wl[lrow] * b2[e * 192 + gcol]);
            atomicAdd(&t[(size_t)rl[lrow] * DD + gcol], add);
        }
    }
}

// ---------------- banded attention: fp32 qkv in, split-pair o out ----------------
__global__ __launch_bounds__(256) void attn_kernel(
    const float* __restrict__ qkv, const float* __restrict__ temp,
    ushort* __restrict__ o)
{
    __shared__ float q[65][64], k[65][64], v[65][64];
    __shared__ float p[65][8];
    int bh = blockIdx.x;
    int b = bh / 3, h = bh % 3;
    int tid = threadIdx.x;
    float coef = 0.125f / temp[h];
    const float* base = qkv + (size_t)b * 65 * 576 + h * 64;
    for (int idx = tid; idx < 65 * 64; idx += 256) {
        int i = idx >> 6, d = idx & 63;
        q[i][d] = base[(size_t)i * 576 + d];
        k[i][d] = base[(size_t)i * 576 + 192 + d];
        v[i][d] = base[(size_t)i * 576 + 384 + d];
    }
    __syncthreads();
    if (tid < 65) {
        int i = tid;
        float sc[7];
        float mx = -1e30f;
        #pragma unroll
        for (int jo = 0; jo < 7; jo++) {
            int j = i - 3 + jo;
            if (j >= 0 && j < 65) {
                float s = 0.f;
                #pragma unroll
                for (int d = 0; d < 64; d++) s += q[i][d] * k[j][d];
                sc[jo] = s * coef;
                mx = fmaxf(mx, sc[jo]);
            } else sc[jo] = -1e30f;
        }
        float sum = 0.f;
        #pragma unroll
        for (int jo = 0; jo < 7; jo++) {
            float e = expf(sc[jo] - mx);
            p[i][jo] = e;
            sum += e;
        }
        float inv = 1.0f / sum;
        #pragma unroll
        for (int jo = 0; jo < 7; jo++) p[i][jo] *= inv;
    }
    __syncthreads();
    for (int idx = tid; idx < 65 * 64; idx += 256) {
        int i = idx >> 6, d = idx & 63;
        float s = 0.f;
        #pragma unroll
        for (int jo = 0; jo < 7; jo++) {
            int j = i - 3 + jo;
            if (j >= 0 && j < 65) s += p[i][jo] * v[j][d];
        }
        int col = h * 64 + d;
        int pp = col >> 3, pos = col & 7;
        size_t rb = ((size_t)b * 65 + i) * 384;
        ushort hi = f2b(s);
        o[rb + pp * 16 + pos] = hi;
        o[rb + pp * 16 + 8 + pos] = f2b(s - b2f(hi));
    }
}

// ---------------- hyper head (fp32) ----------------
__global__ __launch_bounds__(128) void head_kernel(
    const float* __restrict__ cls, const float* __restrict__ hc_w,
    const float* __restrict__ hc_b, const float* __restrict__ head_w,
    const float* __restrict__ head_b, float* __restrict__ out)
{
    __shared__ float c[192];
    __shared__ float hh[384];
    int b = blockIdx.x, tid = threadIdx.x;
    for (int i = tid; i < 192; i += 128) c[i] = cls[(size_t)b * 192 + i];
    __syncthreads();
    for (int i = tid; i < 384; i += 128) {
        int k = i / 96, o = i % 96;
        float s = hc_b[i];
        #pragma unroll
        for (int j = 0; j < 4; j++) {
            int pp = (k - j + 4) & 3;
            const float* w = hc_w + ((size_t)pp * 96 + o) * 48;
            const float* xv = c + j * 48;
            #pragma unroll
            for (int cc = 0; cc < 48; cc++) s += xv[cc] * w[cc];
        }
        hh[i] = gelu_f(s);
    }
    __syncthreads();
    for (int i = tid; i < 100; i += 128) {
        float s = head_b[i];
        const float* w = head_w + (size_t)i * 384;
        for (int kk = 0; kk < 384; kk++) s += hh[kk] * w[kk];
        out[(size_t)b * 100 + i] = s;
    }
}

extern "C" void kernel_launch(void* const* d_in, const int* in_sizes, int n_in,
                              void* d_out, int out_size, void* d_ws, size_t ws_size,
                              hipStream_t stream)
{
    const float* x        = (const float*)d_in[0];
    const float* conv_w   = (const float*)d_in[1];
    const float* conv_b   = (const float*)d_in[2];
    const float* pe_g     = (const float*)d_in[3];
    const float* pe_b     = (const float*)d_in[4];
    const float* cls_tok  = (const float*)d_in[5];
    const float* pos      = (const float*)d_in[6];
    const float* n1_g     = (const float*)d_in[7];
    const float* n1_b     = (const float*)d_in[8];
    const float* qkv_w    = (const float*)d_in[9];
    const float* temp     = (const float*)d_in[10];
    const float* proj_w   = (const float*)d_in[11];
    const float* proj_b   = (const float*)d_in[12];
    const float* n2_g     = (const float*)d_in[13];
    const float* n2_b     = (const float*)d_in[14];
    const float* gate_w   = (const float*)d_in[15];
    const float* gate_b   = (const float*)d_in[16];
    const float* e_w1     = (const float*)d_in[17];
    const float* e_b1     = (const float*)d_in[18];
    const float* e_w2     = (const float*)d_in[19];
    const float* e_b2     = (const float*)d_in[20];
    const float* attn_sc  = (const float*)d_in[21];
    const float* mlp_sc   = (const float*)d_in[22];
    const float* norm_g   = (const float*)d_in[23];
    const float* norm_b   = (const float*)d_in[24];
    const float* hc_w     = (const float*)d_in[25];
    const float* hc_b     = (const float*)d_in[26];
    const float* head_w   = (const float*)d_in[27];
    const float* head_b   = (const float*)d_in[28];

    // ---- ws layout ----
    char* base = (char*)d_ws;
    float*  t     = (float*)base;   base += (size_t)ROWS * DD * 4;        // 6.39MB
    int4*   gwrow = (int4*)base;    base += (size_t)ROWS * 16;            // 133KB
    int*    cnts  = (int*)base;     base += (size_t)12 * 4 * sizeof(int) + 64;
    int*    elist = (int*)base;     base += (size_t)4 * ROWS * 4;         // 133KB
    float*  ewls  = (float*)base;   base += (size_t)4 * ROWS * 4;         // 133KB
    float*  ycls  = (float*)base;   base += (size_t)128 * DD * 4;         // 98KB
    ushort* ysp   = (ushort*)base;  base += (size_t)ROWS * 384 * 2;       // 6.39MB
    ushort* osp   = (ushort*)base;  base += (size_t)ROWS * 384 * 2;       // 6.39MB
    _Float16* yhb = (_Float16*)base; base += (size_t)ROWS * DD * 2;       // 3.19MB
    float*  qkvf  = (float*)base;   base += (size_t)ROWS * 576 * 4;       // 19.2MB
    ushort* qkvw_sp = (ushort*)base; base += (size_t)12 * 576 * 384 * 2;   // 5.3MB
    ushort* projw_sp = (ushort*)base; base += (size_t)12 * 192 * 384 * 2;  // 1.8MB
    _Float16* ew1_h = (_Float16*)base; base += (size_t)12 * 1536 * 192 * 2; // 7.1MB
    _Float16* ew2_h = (_Float16*)base; base += (size_t)12 * 192 * 1536 * 2; // 7.1MB

    hipMemsetAsync(cnts, 0, 12 * 4 * sizeof(int), stream);

    // ---- weight conversion ----
    {
        long np = (long)12 * 576 * 192 / 8;
        cvt_split_kernel<<<(int)((np + 255) / 256), 256, 0, stream>>>(qkv_w, qkvw_sp, np);
        np = (long)12 * 192 * 192 / 8;
        cvt_split_kernel<<<(int)((np + 255) / 256), 256, 0, stream>>>(proj_w, projw_sp, np);
        long n8 = (long)12 * 1536 * 192 / 8;
        cvt_h_kernel<<<(int)((n8 + 255) / 256), 256, 0, stream>>>(e_w1, ew1_h, n8);
        long n = (long)12 * 192 * 192;
        permw2h_kernel<<<(int)((n + 255) / 256), 256, 0, stream>>>(e_w2, ew2_h);
    }

    embed_kernel<<<128 * 65, 192, 0, stream>>>(x, conv_w, conv_b, pe_g, pe_b, cls_tok, pos, t);

    for (int l = 0; l < 12; l++) {
        ln_kernel<<<ROWS / 4, 256, 0, stream>>>(
            t, nullptr, ysp, nullptr, n1_g + l * DD, n1_b + l * DD, DD, ROWS,
            nullptr, nullptr, nullptr);
        mfma_gemm<0><<<dim3(130, 9), 256, 0, stream>>>(
            ysp, qkvw_sp + (size_t)l * 576 * 384, 576, 192, qkvf, nullptr, nullptr, nullptr);
        attn_kernel<<<128 * 3, 256, 0, stream>>>(qkvf, temp + l * 3, osp);
        mfma_gemm<2><<<dim3(130, 3), 256, 0, stream>>>(
            osp, projw_sp + (size_t)l * 192 * 384, 192, 192,
            nullptr, t, proj_b + l * DD, attn_sc + l);
        ln_kernel<<<ROWS / 4, 256, 0, stream>>>(
            t, nullptr, nullptr, yhb, n2_g + l * DD, n2_b + l * DD, DD, ROWS,
            gate_w + (size_t)l * 4 * DD, gate_b + l * 4, gwrow);
        gate_build_kernel<<<(ROWS + 255) / 256, 256, 0, stream>>>(
            gwrow, cnts + l * 4, elist, ewls, ROWS);
        moe_kernel<<<dim3(260, 4), 256, 0, stream>>>(
            yhb, ew1_h + (size_t)l * 1536 * 192, ew2_h + (size_t)l * 192 * 1536,
            e_b1 + (size_t)l * 1536, e_b2 + (size_t)l * 4 * 192, mlp_sc + l,
            cnts + l * 4, elist, ewls, t);
    }

    ln_kernel<<<32, 256, 0, stream>>>(
        t, ycls, nullptr, nullptr, norm_g, norm_b, (long)65 * DD, 128,
        nullptr, nullptr, nullptr);
    head_kernel<<<128, 128, 0, stream>>>(ycls, hc_w, hc_b, head_w, head_b, (float*)d_out);
}

// Round 8
// 1340.531 us; speedup vs baseline: 1.6303x; 1.0921x over previous
//
#include <hip/hip_runtime.h>
#include <cmath>

// Shapes: B=128, D=192, DEPTH=12, H=3(hd=64), E=4, N=65(tokens), NC=100, WIN_HALF=3
#define ROWS 8320
#define DD   192

typedef __attribute__((ext_vector_type(8))) _Float16 half8;
typedef __attribute__((ext_vector_type(4))) float floatx4;

#define GLD16(gp, lp) __builtin_amdgcn_global_load_lds( \
    (const __attribute__((address_space(1))) void*)(gp), \
    (__attribute__((address_space(3))) void*)(lp), 16, 0, 0)

#define MFMA_F16 __builtin_amdgcn_mfma_f32_16x16x32_f16

__device__ __forceinline__ float gelu_f(float x) {
    return 0.5f * x * (1.0f + erff(x * 0.70710678118654752440f));
}

// block-wide sum for blockDim.x == 192 (embed only)
__device__ __forceinline__ float blk_sum_192(float v, float* sbuf) {
    int tid = threadIdx.x;
    sbuf[tid] = v;
    __syncthreads();
    for (int off = 96; off >= 3; off >>= 1) {
        if (tid < off) sbuf[tid] += sbuf[tid + off];
        __syncthreads();
    }
    float r = sbuf[0] + sbuf[1] + sbuf[2];
    __syncthreads();
    return r;
}

// ---------------- flat fp32 -> fp16 ----------------
__global__ __launch_bounds__(256) void cvt_h_kernel(
    const float* __restrict__ s, _Float16* __restrict__ d, long n8)
{
    long i = (long)blockIdx.x * 256 + threadIdx.x;
    if (i >= n8) return;
    const float* sp = s + i * 8;
    _Float16* dp = d + i * 8;
    #pragma unroll
    for (int j = 0; j < 8; j++) dp[j] = (_Float16)sp[j];
}

// e_w2 (12,4,192,384) -> fp16 cat layout [l][n][K'=1536] with col = e*384+k
__global__ __launch_bounds__(256) void permw2h_kernel(
    const float* __restrict__ s, _Float16* __restrict__ d)
{
    long i = (long)blockIdx.x * 256 + threadIdx.x;   // (l, n, p), p in 0..191
    if (i >= (long)12 * 192 * 192) return;
    int l = (int)(i / (192 * 192));
    int rem = (int)(i % (192 * 192));
    int n = rem / 192, p = rem % 192;
    int c0 = p * 8;
    int e = c0 / 384, k0 = c0 % 384;
    const float* sp = s + (((size_t)l * 4 + e) * 192 + n) * 384 + k0;
    _Float16* dp = d + i * 8;
    #pragma unroll
    for (int j = 0; j < 8; j++) dp[j] = (_Float16)sp[j];
}

// ---------------- patch embed + LN + cls + pos (fp32) ----------------
__global__ __launch_bounds__(192) void embed_kernel(
    const float* __restrict__ x, const float* __restrict__ conv_w,
    const float* __restrict__ conv_b, const float* __restrict__ pe_g,
    const float* __restrict__ pe_b, const float* __restrict__ cls_tok,
    const float* __restrict__ pos, float* __restrict__ t)
{
    __shared__ float patch[48];
    __shared__ float red[192];
    int blk = blockIdx.x;
    int b = blk / 65, n = blk % 65;
    int tid = threadIdx.x;
    if (n == 0) {
        t[(size_t)b * 65 * DD + tid] = cls_tok[tid] + pos[tid];
        return;
    }
    int p = n - 1, gy = p / 8, gx = p % 8;
    if (tid < 48) {
        int c = tid / 16, iy = (tid % 16) / 4, ix = tid % 4;
        patch[tid] = x[((size_t)b * 3 + c) * 1024 + (size_t)(gy * 4 + iy) * 32 + (gx * 4 + ix)];
    }
    __syncthreads();
    float s = conv_b[tid];
    const float* w = conv_w + (size_t)tid * 48;
    #pragma unroll
    for (int f = 0; f < 48; f++) s += patch[f] * w[f];
    float mean = blk_sum_192(s, red) * (1.0f / 192.0f);
    float d = s - mean;
    float var = blk_sum_192(d * d, red) * (1.0f / 192.0f);
    float o = d * rsqrtf(var + 1e-5f) * pe_g[tid] + pe_b[tid];
    t[((size_t)b * 65 + n) * DD + tid] = o + pos[(size_t)n * DD + tid];
}

// ---------------- LayerNorm, wave-per-row (4 rows/block, shuffle-only) ----------------
// optional: fold MoE contribs ctb[row][2][192] into the input (and write t back via tout)
// outputs (each optional): yf fp32, yh fp16
// fused gate: softmax(y@gwm^T+gb) top2 -> gwout int4 {e0,e1,bits(w0),bits(w1)}
__global__ __launch_bounds__(256) void ln_kernel(
    const float* __restrict__ in, const float* __restrict__ ctb,
    float* __restrict__ tout,
    float* __restrict__ yf, _Float16* __restrict__ yh,
    const float* __restrict__ g, const float* __restrict__ bb, long in_stride, int nrows,
    const float* __restrict__ gwm, const float* __restrict__ gb,
    int4* __restrict__ gwout)
{
    int wave = threadIdx.x >> 6, lane = threadIdx.x & 63;
    int r = blockIdx.x * 4 + wave;
    if (r >= nrows) return;
    const float* row = in + (size_t)r * in_stride;
    float v0 = row[lane], v1 = row[lane + 64], v2 = row[lane + 128];
    if (ctb) {
        long gr = (long)r * (in_stride / DD);
        const float* cb = ctb + gr * 384;
        v0 += cb[lane] + cb[192 + lane];
        v1 += cb[lane + 64] + cb[256 + lane];
        v2 += cb[lane + 128] + cb[320 + lane];
        if (tout) {
            float* tr = tout + (size_t)r * in_stride;
            tr[lane] = v0; tr[lane + 64] = v1; tr[lane + 128] = v2;
        }
    }
    float s = v0 + v1 + v2;
    #pragma unroll
    for (int off = 32; off > 0; off >>= 1) s += __shfl_xor(s, off);
    float mean = s * (1.0f / 192.0f);
    float d0 = v0 - mean, d1 = v1 - mean, d2 = v2 - mean;
    float q = d0 * d0 + d1 * d1 + d2 * d2;
    #pragma unroll
    for (int off = 32; off > 0; off >>= 1) q += __shfl_xor(q, off);
    float rstd = rsqrtf(q * (1.0f / 192.0f) + 1e-5f);
    float o0 = d0 * rstd * g[lane] + bb[lane];
    float o1 = d1 * rstd * g[lane + 64] + bb[lane + 64];
    float o2 = d2 * rstd * g[lane + 128] + bb[lane + 128];
    if (yf) {
        float* yr = yf + (size_t)r * DD;
        yr[lane] = o0; yr[lane + 64] = o1; yr[lane + 128] = o2;
    }
    if (yh) {
        _Float16* yr = yh + (size_t)r * DD;
        yr[lane] = (_Float16)o0; yr[lane + 64] = (_Float16)o1; yr[lane + 128] = (_Float16)o2;
    }
    if (gwm) {
        float pe[4];
        #pragma unroll
        for (int e = 0; e < 4; e++) {
            const float* w = gwm + (size_t)e * DD;
            pe[e] = o0 * w[lane] + o1 * w[lane + 64] + o2 * w[lane + 128];
            #pragma unroll
            for (int off = 32; off > 0; off >>= 1) pe[e] += __shfl_xor(pe[e], off);
        }
        if (lane == 0) {
            #pragma unroll
            for (int e = 0; e < 4; e++) pe[e] += gb[e];
            float mx = fmaxf(fmaxf(pe[0], pe[1]), fmaxf(pe[2], pe[3]));
            float ex[4];
            #pragma unroll
            for (int e = 0; e < 4; e++) ex[e] = expf(pe[e] - mx);
            int i0 = 0;
            #pragma unroll
            for (int e = 1; e < 4; e++) if (ex[e] > ex[i0]) i0 = e;
            int i1 = (i0 == 0) ? 1 : 0;
            #pragma unroll
            for (int e = 0; e < 4; e++) if (e != i0 && ex[e] > ex[i1]) i1 = e;
            float denom = ex[i0] + ex[i1];
            int4 o4;
            o4.x = i0; o4.y = i1;
            o4.z = __float_as_int(ex[i0] / denom);
            o4.w = __float_as_int(ex[i1] / denom);
            gwout[r] = o4;
        }
    }
}

// ---------------- build per-expert row lists; entry = (row<<1)|rank ----------------
__global__ __launch_bounds__(256) void gate_build_kernel(
    const int4* __restrict__ gwrow, int* __restrict__ cnt,
    int* __restrict__ list, float* __restrict__ wlist, int rows)
{
    int r = blockIdx.x * 256 + threadIdx.x;
    int lane = threadIdx.x & 63;
    bool active = r < rows;
    int4 gv = active ? gwrow[r] : int4{-1, -1, 0, 0};
    #pragma unroll
    for (int e = 0; e < 4; e++) {
        bool sel = active && (gv.x == e || gv.y == e);
        int rank = (gv.x == e) ? 0 : 1;
        float w = (gv.x == e) ? __int_as_float(gv.z) : __int_as_float(gv.w);
        unsigned long long mask = __ballot(sel);
        int cw = __popcll(mask);
        if (cw) {
            int leader = __ffsll((long long)mask) - 1;
            int base = 0;
            if (lane == leader) base = atomicAdd(&cnt[e], cw);
            base = __shfl(base, leader);
            if (sel) {
                int idx = base + __popcll(mask & ((1ULL << lane) - 1ULL));
                list[(size_t)e * ROWS + idx] = (r << 1) | rank;
                wlist[(size_t)e * ROWS + idx] = w;
            }
        }
    }
}

// ---------------- fp16 MFMA GEMM, K=192: C[M,N] = A[M,192] @ W[N,192]^T ----------------
// MODE 0: out fp16 packed [M][Nn]   (qkv; no bias)
// MODE 2: t[r*192+n] += scale[0]*(acc + bias[n])   (proj)
template <int MODE>
__global__ __launch_bounds__(256) void gemm_h(
    const _Float16* __restrict__ A, const _Float16* __restrict__ W,
    int Nn, _Float16* __restrict__ outH, float* __restrict__ t,
    const float* __restrict__ bias, const float* __restrict__ scale)
{
    __shared__ __align__(16) _Float16 As[64 * 192];   // 24KB
    __shared__ __align__(16) _Float16 Ws[64 * 192];   // 24KB
    const int tid = threadIdx.x;
    const int lane = tid & 63, wave = tid >> 6;
    const int m0 = blockIdx.x * 64, n0 = blockIdx.y * 64;
    const int wm = (wave & 1) * 32, wn = (wave >> 1) * 32;
    const int lr = lane & 15, quad = lane >> 4;

    #pragma unroll
    for (int i = 0; i < 6; i++) {
        int s = (wave * 6 + i) * 64 + lane;
        int rr = s / 24, c = s % 24;
        GLD16(A + (size_t)(m0 + rr) * 192 + (c ^ (rr & 7)) * 8,
              (char*)As + (size_t)(wave * 6 + i) * 1024);
        GLD16(W + (size_t)(n0 + rr) * 192 + (c ^ (rr & 7)) * 8,
              (char*)Ws + (size_t)(wave * 6 + i) * 1024);
    }
    __syncthreads();

    floatx4 zero = {0.f, 0.f, 0.f, 0.f};
    floatx4 acc[2][2];
    acc[0][0] = zero; acc[0][1] = zero; acc[1][0] = zero; acc[1][1] = zero;

    #pragma unroll
    for (int m = 0; m < 6; m++) {
        int ch = m * 4 + quad;
        half8 a[2], w[2];
        #pragma unroll
        for (int ti = 0; ti < 2; ti++) {
            int ar = wm + ti * 16 + lr;
            a[ti] = *(const half8*)(As + ((size_t)ar * 24 + (ch ^ (ar & 7))) * 8);
            int cr = wn + ti * 16 + lr;
            w[ti] = *(const half8*)(Ws + ((size_t)cr * 24 + (ch ^ (cr & 7))) * 8);
        }
        #pragma unroll
        for (int ti = 0; ti < 2; ti++)
            #pragma unroll
            for (int tj = 0; tj < 2; tj++)
                acc[ti][tj] = MFMA_F16(a[ti], w[tj], acc[ti][tj], 0, 0, 0);
    }

    float sc = (MODE == 2) ? scale[0] : 0.f;
    #pragma unroll
    for (int ti = 0; ti < 2; ti++)
        #pragma unroll
        for (int tj = 0; tj < 2; tj++)
            #pragma unroll
            for (int r = 0; r < 4; r++) {
                int grow = m0 + wm + ti * 16 + quad * 4 + r;
                int gcol = n0 + wn + tj * 16 + lr;
                float v = acc[ti][tj][r];
                if (MODE == 0) {
                    float vp = __shfl_xor(v, 1);
                    if ((lane & 1) == 0) {
                        union { _Float16 h[2]; unsigned u; } pk;
                        pk.h[0] = (_Float16)v;
                        pk.h[1] = (_Float16)vp;
                        *(unsigned*)(outH + (size_t)grow * Nn + (gcol & ~1)) = pk.u;
                    }
                } else {
                    t[(size_t)grow * DD + gcol] += sc * (v + bias[gcol]);
                }
            }
}

// ---------------- fused MoE: fp16, expert-parallel row-gather, rank-indexed output ----------------
// grid (260, 4): block = 32 gathered rows of expert e. 6 iters of 64 h-cols.
// ctb[row][rank][192] = mlp_sc * w * (gelu(y@w1_e^T+b1_e)@w2_e^T + b2_e)  (plain stores)
__global__ __launch_bounds__(256) void moe_kernel(
    const _Float16* __restrict__ yh, const _Float16* __restrict__ w1,
    const _Float16* __restrict__ w2, const float* __restrict__ b1,
    const float* __restrict__ b2, const float* __restrict__ scale,
    const int* __restrict__ cnt, const int* __restrict__ list,
    const float* __restrict__ wlist, float* __restrict__ ctb)
{
    __shared__ __align__(16) _Float16 As[32 * 192];   // 12KB
    __shared__ __align__(16) _Float16 W1s[64 * 192];  // 24KB
    __shared__ __align__(16) _Float16 W2s[192 * 64];  // 24KB
    __shared__ __align__(16) _Float16 Hs[32 * 64];    // 4KB
    __shared__ int   rl[32];
    __shared__ int   rk[32];
    __shared__ float wl[32];
    const int e  = blockIdx.y;
    const int cnte = cnt[e];
    const int r0 = blockIdx.x * 32;
    if (r0 >= cnte) return;
    const int tid = threadIdx.x;
    const int lane = tid & 63, wave = tid >> 6;
    const int lr = lane & 15, quad = lane >> 4;
    const int wr = (wave & 1) * 16;
    const int wc1 = (wave >> 1) * 16;
    const int wc2 = (wave >> 1) * 96;

    if (tid < 32) {
        int sl = r0 + tid;
        bool ok = sl < cnte;
        int v = ok ? list[(size_t)e * ROWS + sl] : 0;
        rl[tid] = ok ? (v >> 1) : 0;
        rk[tid] = ok ? (v & 1) : -1;
        wl[tid] = ok ? wlist[(size_t)e * ROWS + sl] : 0.f;
    }
    __syncthreads();

    // stage A: gathered rows, 24 chunks each (3/thread)
    #pragma unroll
    for (int i = 0; i < 3; i++) {
        int s = (wave * 3 + i) * 64 + lane;
        int rr = s / 24, c = s % 24;
        GLD16(yh + (size_t)rl[rr] * 192 + (c ^ (rr & 7)) * 8,
              (char*)As + (size_t)(wave * 3 + i) * 1024);
    }
    // stage W1 chunk0: 64 hcols x 24 chunks (6/thread)
    #pragma unroll
    for (int i = 0; i < 6; i++) {
        int s = (wave * 6 + i) * 64 + lane;
        int rr = s / 24, c = s % 24;
        GLD16(w1 + ((size_t)e * 384 + rr) * 192 + (c ^ (rr & 7)) * 8,
              (char*)W1s + (size_t)(wave * 6 + i) * 1024);
    }
    __syncthreads();

    floatx4 zero = {0.f, 0.f, 0.f, 0.f};
    floatx4 acc2[6];
    #pragma unroll
    for (int j = 0; j < 6; j++) acc2[j] = zero;

    for (int nc = 0; nc < 6; nc++) {
        int ncg = e * 6 + nc;
        // issue W2[ncg] (fly during gemm1)
        #pragma unroll
        for (int i = 0; i < 6; i++) {
            int s = (wave * 6 + i) * 64 + lane;
            int n = s >> 3, c = s & 7;
            GLD16(w2 + (size_t)n * 1536 + (ncg * 8 + (c ^ (n & 7))) * 8,
                  (char*)W2s + (size_t)(wave * 6 + i) * 1024);
        }
        // gemm1: 32 rows x 64 hcols
        floatx4 acc1[2];
        acc1[0] = zero; acc1[1] = zero;
        #pragma unroll
        for (int m = 0; m < 6; m++) {
            int ar = wr + lr;
            int ch = m * 4 + quad;
            half8 a = *(const half8*)(As + ((size_t)ar * 24 + (ch ^ (ar & 7))) * 8);
            #pragma unroll
            for (int tc = 0; tc < 2; tc++) {
                int cr = wc1 + tc * 32 + lr;
                half8 w = *(const half8*)(W1s + ((size_t)cr * 24 + (ch ^ (cr & 7))) * 8);
                acc1[tc] = MFMA_F16(a, w, acc1[tc], 0, 0, 0);
            }
        }
        // epilogue: gelu*w -> Hs fp16, packed 32-bit writes
        #pragma unroll
        for (int tc = 0; tc < 2; tc++)
            #pragma unroll
            for (int r = 0; r < 4; r++) {
                int hrow = wr + quad * 4 + r;
                int hcol = wc1 + tc * 32 + lr;
                float v = gelu_f(acc1[tc][r] + b1[64 * ncg + hcol]) * wl[hrow];
                float vp = __shfl_xor(v, 1);
                if ((lane & 1) == 0) {
                    union { _Float16 h[2]; unsigned u; } pk;
                    pk.h[0] = (_Float16)v;
                    pk.h[1] = (_Float16)vp;
                    int cl = (hcol >> 3) ^ (hrow & 7);
                    *(unsigned*)(Hs + ((size_t)hrow * 8 + cl) * 8 + (hcol & 7)) = pk.u;
                }
            }
        __syncthreads();
        if (nc < 5) {   // prefetch W1[nc+1] during gemm2
            #pragma unroll
            for (int i = 0; i < 6; i++) {
                int s = (wave * 6 + i) * 64 + lane;
                int rr = s / 24, c = s % 24;
                GLD16(w1 + ((size_t)e * 384 + (nc + 1) * 64 + rr) * 192 + (c ^ (rr & 7)) * 8,
                      (char*)W1s + (size_t)(wave * 6 + i) * 1024);
            }
        }
        // gemm2: out[32][192] partial, K=64
        #pragma unroll
        for (int kk = 0; kk < 2; kk++) {
            int ar = wr + lr;
            int ch = kk * 4 + quad;
            half8 a = *(const half8*)(Hs + ((size_t)ar * 8 + (ch ^ (ar & 7))) * 8);
            #pragma unroll
            for (int tj = 0; tj < 6; tj++) {
                int cr = wc2 + tj * 16 + lr;
                half8 w = *(const half8*)(W2s + ((size_t)cr * 8 + (ch ^ (cr & 7))) * 8);
                acc2[tj] = MFMA_F16(a, w, acc2[tj], 0, 0, 0);
            }
        }
        __syncthreads();
    }

    float sc = scale[0];
    #pragma unroll
    for (int tj = 0; tj < 6; tj++) {
        int gcol = wc2 + tj * 16 + lr;
        #pragma unroll
        for (int r = 0; r < 4; r++) {
            int lrow = wr + quad * 4 + r;
            int rank = rk[lrow];
            if (rank >= 0) {
                float v = sc * (acc2[tj][r] + wl[lrow] * b2[e * 192 + gcol]);
                ctb[((size_t)rl[lrow] * 2 + rank) * 192 + gcol] = v;
            }
        }
    }
}

// ---------------- banded attention: fp16 in/out, fp32 compute ----------------
__global__ __launch_bounds__(256) void attn_kernel(
    const _Float16* __restrict__ qkv, const float* __restrict__ temp,
    _Float16* __restrict__ o)
{
    __shared__ float q[65][64], k[65][64], v[65][64];
    __shared__ float p[65][8];
    int bh = blockIdx.x;
    int b = bh / 3, h = bh % 3;
    int tid = threadIdx.x;
    float coef = 0.125f / temp[h];
    const _Float16* base = qkv + (size_t)b * 65 * 576 + h * 64;
    for (int idx = tid; idx < 65 * 64; idx += 256) {
        int i = idx >> 6, d = idx & 63;
        q[i][d] = (float)base[(size_t)i * 576 + d];
        k[i][d] = (float)base[(size_t)i * 576 + 192 + d];
        v[i][d] = (float)base[(size_t)i * 576 + 384 + d];
    }
    __syncthreads();
    if (tid < 65) {
        int i = tid;
        float sc[7];
        float mx = -1e30f;
        #pragma unroll
        for (int jo = 0; jo < 7; jo++) {
            int j = i - 3 + jo;
            if (j >= 0 && j < 65) {
                float s = 0.f;
                #pragma unroll
                for (int d = 0; d < 64; d++) s += q[i][d] * k[j][d];
                sc[jo] = s * coef;
                mx = fmaxf(mx, sc[jo]);
            } else sc[jo] = -1e30f;
        }
        float sum = 0.f;
        #pragma unroll
        for (int jo = 0; jo < 7; jo++) {
            float e = expf(sc[jo] - mx);
            p[i][jo] = e;
            sum += e;
        }
        float inv = 1.0f / sum;
        #pragma unroll
        for (int jo = 0; jo < 7; jo++) p[i][jo] *= inv;
    }
    __syncthreads();
    for (int idx = tid; idx < 65 * 64; idx += 256) {
        int i = idx >> 6, d = idx & 63;
        float s = 0.f;
        #pragma unroll
        for (int jo = 0; jo < 7; jo++) {
            int j = i - 3 + jo;
            if (j >= 0 && j < 65) s += p[i][jo] * v[j][d];
        }
        o[((size_t)b * 65 + i) * 192 + h * 64 + d] = (_Float16)s;
    }
}

// ---------------- hyper head (fp32) ----------------
__global__ __launch_bounds__(128) void head_kernel(
    const float* __restrict__ cls, const float* __restrict__ hc_w,
    const float* __restrict__ hc_b, const float* __restrict__ head_w,
    const float* __restrict__ head_b, float* __restrict__ out)
{
    __shared__ float c[192];
    __shared__ float hh[384];
    int b = blockIdx.x, tid = threadIdx.x;
    for (int i = tid; i < 192; i += 128) c[i] = cls[(size_t)b * 192 + i];
    __syncthreads();
    for (int i = tid; i < 384; i += 128) {
        int k = i / 96, o = i % 96;
        float s = hc_b[i];
        #pragma unroll
        for (int j = 0; j < 4; j++) {
            int pp = (k - j + 4) & 3;
            const float* w = hc_w + ((size_t)pp * 96 + o) * 48;
            const float* xv = c + j * 48;
            #pragma unroll
            for (int cc = 0; cc < 48; cc++) s += xv[cc] * w[cc];
        }
        hh[i] = gelu_f(s);
    }
    __syncthreads();
    for (int i = tid; i < 100; i += 128) {
        float s = head_b[i];
        const float* w = head_w + (size_t)i * 384;
        for (int kk = 0; kk < 384; kk++) s += hh[kk] * w[kk];
        out[(size_t)b * 100 + i] = s;
    }
}

extern "C" void kernel_launch(void* const* d_in, const int* in_sizes, int n_in,
                              void* d_out, int out_size, void* d_ws, size_t ws_size,
                              hipStream_t stream)
{
    const float* x        = (const float*)d_in[0];
    const float* conv_w   = (const float*)d_in[1];
    const float* conv_b   = (const float*)d_in[2];
    const float* pe_g     = (const float*)d_in[3];
    const float* pe_b     = (const float*)d_in[4];
    const float* cls_tok  = (const float*)d_in[5];
    const float* pos      = (const float*)d_in[6];
    const float* n1_g     = (const float*)d_in[7];
    const float* n1_b     = (const float*)d_in[8];
    const float* qkv_w    = (const float*)d_in[9];
    const float* temp     = (const float*)d_in[10];
    const float* proj_w   = (const float*)d_in[11];
    const float* proj_b   = (const float*)d_in[12];
    const float* n2_g     = (const float*)d_in[13];
    const float* n2_b     = (const float*)d_in[14];
    const float* gate_w   = (const float*)d_in[15];
    const float* gate_b   = (const float*)d_in[16];
    const float* e_w1     = (const float*)d_in[17];
    const float* e_b1     = (const float*)d_in[18];
    const float* e_w2     = (const float*)d_in[19];
    const float* e_b2     = (const float*)d_in[20];
    const float* attn_sc  = (const float*)d_in[21];
    const float* mlp_sc   = (const float*)d_in[22];
    const float* norm_g   = (const float*)d_in[23];
    const float* norm_b   = (const float*)d_in[24];
    const float* hc_w     = (const float*)d_in[25];
    const float* hc_b     = (const float*)d_in[26];
    const float* head_w   = (const float*)d_in[27];
    const float* head_b   = (const float*)d_in[28];

    // ---- ws layout ----
    char* base = (char*)d_ws;
    float*  t     = (float*)base;   base += (size_t)ROWS * DD * 4;        // 6.39MB
    float*  ctb   = (float*)base;   base += (size_t)ROWS * 384 * 4;       // 12.8MB
    int4*   gwrow = (int4*)base;    base += (size_t)ROWS * 16;            // 133KB
    int*    cnts  = (int*)base;     base += (size_t)12 * 4 * sizeof(int) + 64;
    int*    elist = (int*)base;     base += (size_t)4 * ROWS * 4;         // 133KB
    float*  ewls  = (float*)base;   base += (size_t)4 * ROWS * 4;         // 133KB
    float*  ycls  = (float*)base;   base += (size_t)128 * DD * 4;         // 98KB
    _Float16* yhb = (_Float16*)base; base += (size_t)ROWS * DD * 2;       // 3.19MB
    _Float16* qkvh = (_Float16*)base; base += (size_t)ROWS * 576 * 2;     // 9.58MB
    _Float16* osph = (_Float16*)base; base += (size_t)ROWS * DD * 2;      // 3.19MB
    _Float16* qkvw_h = (_Float16*)base; base += (size_t)12 * 576 * 192 * 2;  // 2.65MB
    _Float16* projw_h = (_Float16*)base; base += (size_t)12 * 192 * 192 * 2; // 0.88MB
    _Float16* ew1_h = (_Float16*)base; base += (size_t)12 * 1536 * 192 * 2;  // 7.1MB
    _Float16* ew2_h = (_Float16*)base; base += (size_t)12 * 192 * 1536 * 2;  // 7.1MB

    hipMemsetAsync(cnts, 0, 12 * 4 * sizeof(int), stream);

    // ---- weight conversion ----
    {
        long n8 = (long)12 * 576 * 192 / 8;
        cvt_h_kernel<<<(int)((n8 + 255) / 256), 256, 0, stream>>>(qkv_w, qkvw_h, n8);
        n8 = (long)12 * 192 * 192 / 8;
        cvt_h_kernel<<<(int)((n8 + 255) / 256), 256, 0, stream>>>(proj_w, projw_h, n8);
        n8 = (long)12 * 1536 * 192 / 8;
        cvt_h_kernel<<<(int)((n8 + 255) / 256), 256, 0, stream>>>(e_w1, ew1_h, n8);
        long n = (long)12 * 192 * 192;
        permw2h_kernel<<<(int)((n + 255) / 256), 256, 0, stream>>>(e_w2, ew2_h);
    }

    embed_kernel<<<128 * 65, 192, 0, stream>>>(x, conv_w, conv_b, pe_g, pe_b, cls_tok, pos, t);

    for (int l = 0; l < 12; l++) {
        // ln1: fold previous layer's MoE contribs into t (l>0), emit fp16 y
        ln_kernel<<<ROWS / 4, 256, 0, stream>>>(
            t, (l > 0) ? ctb : nullptr, (l > 0) ? t : nullptr,
            nullptr, yhb, n1_g + l * DD, n1_b + l * DD, DD, ROWS,
            nullptr, nullptr, nullptr);
        gemm_h<0><<<dim3(130, 9), 256, 0, stream>>>(
            yhb, qkvw_h + (size_t)l * 576 * 192, 576, qkvh, nullptr, nullptr, nullptr);
        attn_kernel<<<128 * 3, 256, 0, stream>>>(qkvh, temp + l * 3, osph);
        gemm_h<2><<<dim3(130, 3), 256, 0, stream>>>(
            osph, projw_h + (size_t)l * 192 * 192, 192, nullptr, t,
            proj_b + l * DD, attn_sc + l);
        // ln2 + gate
        ln_kernel<<<ROWS / 4, 256, 0, stream>>>(
            t, nullptr, nullptr, nullptr, yhb, n2_g + l * DD, n2_b + l * DD, DD, ROWS,
            gate_w + (size_t)l * 4 * DD, gate_b + l * 4, gwrow);
        gate_build_kernel<<<(ROWS + 255) / 256, 256, 0, stream>>>(
            gwrow, cnts + l * 4, elist, ewls, ROWS);
        moe_kernel<<<dim3(260, 4), 256, 0, stream>>>(
            yhb, ew1_h + (size_t)l * 1536 * 192, ew2_h + (size_t)l * 192 * 1536,
            e_b1 + (size_t)l * 1536, e_b2 + (size_t)l * 4 * 192, mlp_sc + l,
            cnts + l * 4, elist, ewls, ctb);
    }

    // final LN on cls rows: fold last MoE contribs (stride-aware)
    ln_kernel<<<32, 256, 0, stream>>>(
        t, ctb, nullptr, ycls, nullptr, norm_g, norm_b, (long)65 * DD, 128,
        nullptr, nullptr, nullptr);
    head_kernel<<<128, 128, 0, stream>>>(ycls, hc_w, hc_b, head_w, head_b, (float*)d_out);
}